// Round 5
// baseline (643.388 us; speedup 1.0000x reference)
//
#include <hip/hip_runtime.h>
#include <hip/hip_bf16.h>

// ---------------------------------------------------------------------------
// VoxelBackBone8x, R5: bf16 MFMA implicit-GEMM sparse conv, batched gathers.
// R4 lesson: vmcnt is in-order -> interleaving "prefetch A[t+1]; load B[t];
// mfma" makes every MFMA's B-wait drain the A-prefetch too (27 serial latency
// rounds/wave, MfmaUtil 3%). R5 issues A-gathers in big batches (7/14 taps)
// BEFORE any B-load of the batch: one latency round per batch, B-loads only
// re-wait the already-in-flight batch. idx[27] still loaded upfront.
// Verified MFMA layouts (learn_hip m89/m91):
//   A[m=lane&15][k=quad*8+j], B[n=lane&15][k=quad*8+j],
//   C/D col=lane&15, row=quad*4+reg.
// ---------------------------------------------------------------------------

typedef __attribute__((ext_vector_type(8))) short bf16x8;
typedef __attribute__((ext_vector_type(4))) float f32x4;

__device__ inline unsigned short f2bf(float f) {
    unsigned u = __builtin_bit_cast(unsigned, f);
    u += 0x7FFFu + ((u >> 16) & 1u);
    return (unsigned short)(u >> 16);
}

struct ScatterArgs {
    const int* coords[4];
    int* grid[4];
    int n[4];
    int D[4], H[4], W[4];
};

__global__ __launch_bounds__(256) void scatter_grid_all(ScatterArgs a) {
    const int l = blockIdx.y;
    const int i = blockIdx.x * 256 + threadIdx.x;
    if (i >= a.n[l]) return;
    const int* c = a.coords[l] + 4 * i;
    a.grid[l][((c[0] * a.D[l] + c[1]) * a.H[l] + c[2]) * a.W[l] + c[3]] = i;
}

struct PrepArgs {
    const float* src[11];
    unsigned short* dst[11];
    int T[11], CIN[11], COUT[11], total[11];   // total = (T+1)*CIN*COUT
};

// fp32 [t][cin][cout] -> bf16 [t][cout][cin]; pad tap T zeroed
__global__ __launch_bounds__(256) void prep_w_all(PrepArgs a) {
    const int l = blockIdx.y;
    const int i = blockIdx.x * 256 + threadIdx.x;
    if (i >= a.total[l]) return;
    const int COUT = a.COUT[l], CIN = a.CIN[l], T = a.T[l];
    const int co = i % COUT; const int r = i / COUT; const int ci = r % CIN; const int t = r / CIN;
    unsigned short v = (t < T) ? f2bf(a.src[l][i]) : (unsigned short)0;
    a.dst[l][((size_t)t * COUT + co) * CIN + ci] = v;
}

// Layer 0: CIN=4 -> COUT=16, k=3, stride 1, pad 1, fp32 VALU
__global__ __launch_bounds__(256) void sp_conv0(const float* __restrict__ fin,
                                                const int* __restrict__ grid,
                                                const int* __restrict__ oc, int n_out,
                                                const float* __restrict__ w,
                                                float* __restrict__ out,
                                                int D, int H, int W) {
    const int c = threadIdx.x & 15;
    const int p = (blockIdx.x * 256 + threadIdx.x) >> 4;
    if (p >= n_out) return;
    const int b   = oc[4*p+0];
    const int iz0 = oc[4*p+1] - 1;
    const int iy0 = oc[4*p+2] - 1;
    const int ix0 = oc[4*p+3] - 1;
    const int* gb = grid + b * (D * H * W);
    float acc = 0.f;
    for (int kd = 0; kd < 3; ++kd) {
        const int iz = iz0 + kd;
        if ((unsigned)iz >= (unsigned)D) continue;
        for (int kh = 0; kh < 3; ++kh) {
            const int iy = iy0 + kh;
            if ((unsigned)iy >= (unsigned)H) continue;
            for (int kw = 0; kw < 3; ++kw) {
                const int ix = ix0 + kw;
                if ((unsigned)ix >= (unsigned)W) continue;
                const int idx = gb[(iz*H + iy)*W + ix];
                if (idx < 0) continue;
                const float4 v = *(const float4*)(fin + (size_t)idx * 4);
                const float* wp = w + (size_t)((kd*3 + kh)*3 + kw) * 4 * 16 + c;
                acc = fmaf(v.x, wp[0],  acc);
                acc = fmaf(v.y, wp[16], acc);
                acc = fmaf(v.z, wp[32], acc);
                acc = fmaf(v.w, wp[48], acc);
            }
        }
    }
    out[(size_t)p*16 + c] = acc;
}

template<int CIN, int COUT, int KD, int KH, int KW>
__global__ __launch_bounds__(256) void sp_conv_mfma(
    const unsigned short* __restrict__ fin, const int* __restrict__ grid,
    const int* __restrict__ oc, int n_out,
    const unsigned short* __restrict__ wt, float* __restrict__ out,
    float* __restrict__ stats,
    int D, int H, int W, int sz, int sy, int sx, int pz, int py, int px)
{
    constexpr int T  = KD*KH*KW;
    constexpr int NT = COUT/16;
    __shared__ float ls[2*COUT];
    const int lane = threadIdx.x & 63;
    const int wid  = threadIdx.x >> 6;
    const int n    = lane & 15;
    const int quad = lane >> 4;
    const int pbase = blockIdx.x * 64 + wid * 16;

    if (threadIdx.x < 2*COUT) ls[threadIdx.x] = 0.f;

    int pc = pbase + n;
    if (pc > n_out - 1) pc = n_out - 1;
    const int4 cc = ((const int4*)oc)[pc];
    const int* gb = grid + cc.x * (D * H * W);
    const int iz0 = cc.y * sz - pz;
    const int iy0 = cc.z * sy - py;
    const int ix0 = cc.w * sx - px;

    f32x4 acc[NT];
#pragma unroll
    for (int t = 0; t < NT; ++t) acc[t] = (f32x4){0.f, 0.f, 0.f, 0.f};

    if constexpr (CIN >= 32) {
        constexpr int S = CIN/32;
        constexpr int BATCH = (CIN >= 64) ? 7 : 14;   // VGPR-budgeted taps/batch
        // --- all tap indices upfront: one latency round
        int idx[T];
#pragma unroll
        for (int tap = 0; tap < T; ++tap) {
            const int kd = tap/(KH*KW), kr = tap%(KH*KW), kh = kr/KW, kw = kr%KW;
            const int iz = iz0 + kd, iy = iy0 + kh, ix = ix0 + kw;
            idx[tap] = ((unsigned)iz < (unsigned)D && (unsigned)iy < (unsigned)H &&
                        (unsigned)ix < (unsigned)W) ? gb[(iz*H + iy)*W + ix] : -1;
        }
        // --- batched gathers: all A of a batch in flight before any B-load
#pragma unroll
        for (int t0 = 0; t0 < T; t0 += BATCH) {
            bf16x8 a[BATCH][S];
#pragma unroll
            for (int j = 0; j < BATCH; ++j) {
                const int tap = t0 + j;
                if (tap < T) {
#pragma unroll
                    for (int s = 0; s < S; ++s) {
                        a[j][s] = (bf16x8){};
                        if (idx[tap] >= 0)
                            a[j][s] = *(const bf16x8*)(fin + (size_t)idx[tap]*CIN + s*32 + quad*8);
                    }
                }
            }
#pragma unroll
            for (int j = 0; j < BATCH; ++j) {
                const int tap = t0 + j;
                if (tap < T) {
                    const unsigned short* wrow = wt + (size_t)tap*(COUT*CIN) + n*CIN + quad*8;
#pragma unroll
                    for (int s = 0; s < S; ++s)
#pragma unroll
                        for (int t = 0; t < NT; ++t) {
                            bf16x8 b = *(const bf16x8*)(wrow + (size_t)(t*16)*CIN + s*32);
                            acc[t] = __builtin_amdgcn_mfma_f32_16x16x32_bf16(a[j][s], b, acc[t], 0, 0, 0);
                        }
                }
            }
        }
    } else {  // CIN == 16: 2 taps packed per K=32 (quad>>1 picks the tap); one round
        constexpr int KB = (T + 1) / 2;
        int idx[KB], tcv[KB];
        const int cinb = (quad & 1) * 8;
#pragma unroll
        for (int kb = 0; kb < KB; ++kb) {
            const int tap = 2*kb + (quad >> 1);
            const bool tv = (tap < T);
            const int td = tv ? tap : 0;
            const int kd = td/(KH*KW), kr = td%(KH*KW), kh = kr/KW, kw = kr%KW;
            const int iz = iz0 + kd, iy = iy0 + kh, ix = ix0 + kw;
            idx[kb] = (tv && (unsigned)iz < (unsigned)D && (unsigned)iy < (unsigned)H &&
                       (unsigned)ix < (unsigned)W) ? gb[(iz*H + iy)*W + ix] : -1;
            tcv[kb] = tv ? tap : T;   // pad slot zeroed by prep
        }
        bf16x8 a[KB];
#pragma unroll
        for (int kb = 0; kb < KB; ++kb) {
            a[kb] = (bf16x8){};
            if (idx[kb] >= 0) a[kb] = *(const bf16x8*)(fin + (size_t)idx[kb]*16 + cinb);
        }
#pragma unroll
        for (int kb = 0; kb < KB; ++kb) {
#pragma unroll
            for (int t = 0; t < NT; ++t) {
                bf16x8 b = *(const bf16x8*)(wt + ((size_t)tcv[kb]*COUT + t*16 + n)*16 + cinb);
                acc[t] = __builtin_amdgcn_mfma_f32_16x16x32_bf16(a[kb], b, acc[t], 0, 0, 0);
            }
        }
    }

    // --- store raw fp32
#pragma unroll
    for (int t = 0; t < NT; ++t)
#pragma unroll
        for (int r = 0; r < 4; ++r) {
            const int p = pbase + quad*4 + r;
            if (p < n_out) out[(size_t)p * COUT + t*16 + n] = acc[t][r];
        }

    // --- fused BN stats: quad shuffle-reduce -> LDS -> 1 atomic/ch/block
    __syncthreads();
#pragma unroll
    for (int t = 0; t < NT; ++t) {
        float s1 = 0.f, s2 = 0.f;
#pragma unroll
        for (int r = 0; r < 4; ++r) {
            const int p = pbase + quad*4 + r;
            if (p < n_out) { const float v = acc[t][r]; s1 += v; s2 += v*v; }
        }
        s1 += __shfl_xor(s1, 16); s2 += __shfl_xor(s2, 16);
        s1 += __shfl_xor(s1, 32); s2 += __shfl_xor(s2, 32);
        if (quad == 0) {
            atomicAdd(&ls[t*16 + n], s1);
            atomicAdd(&ls[COUT + t*16 + n], s2);
        }
    }
    __syncthreads();
    if (threadIdx.x < 2*COUT) atomicAdd(&stats[threadIdx.x], ls[threadIdx.x]);
}

template<int C>
__global__ __launch_bounds__(256) void reduce_stats(const float* __restrict__ x, int nn,
                                                    float* __restrict__ stats)
{
    constexpr int R = 256 / C;
    __shared__ float s1[256];
    __shared__ float s2[256];
    const int c = threadIdx.x % C;
    const int r = threadIdx.x / C;
    float a1 = 0.f, a2 = 0.f;
    for (int i = blockIdx.x * R + r; i < nn; i += R * gridDim.x) {
        float v = x[(size_t)i*C + c];
        a1 += v;
        a2 += v * v;
    }
    s1[threadIdx.x] = a1;
    s2[threadIdx.x] = a2;
    __syncthreads();
    for (int off = 128; off >= C; off >>= 1) {
        if (threadIdx.x < off) {
            s1[threadIdx.x] += s1[threadIdx.x + off];
            s2[threadIdx.x] += s2[threadIdx.x + off];
        }
        __syncthreads();
    }
    if (threadIdx.x < C) {
        atomicAdd(&stats[c],     s1[threadIdx.x]);
        atomicAdd(&stats[C + c], s2[threadIdx.x]);
    }
}

__device__ inline void stv(float* p, float v)          { *p = v; }
__device__ inline void stv(unsigned short* p, float v) { *p = f2bf(v); }

template<int C, typename OUT>
__global__ __launch_bounds__(256) void bn_relu_apply(const float* __restrict__ x,
                                                     OUT* __restrict__ y, int nn,
                                                     const float* __restrict__ stats,
                                                     const float* __restrict__ gamma,
                                                     const float* __restrict__ beta)
{
    const size_t i = (size_t)blockIdx.x * blockDim.x + threadIdx.x;
    if (i >= (size_t)nn * C) return;
    const int c = (int)(i % C);
    const float inv_n = 1.f / (float)nn;
    const float mu  = stats[c] * inv_n;
    const float var = stats[C + c] * inv_n - mu * mu;
    const float g = gamma[c] * rsqrtf(var + 1e-3f);
    const float v = (x[i] - mu) * g + beta[c];
    stv(y + i, v > 0.f ? v : 0.f);
}

extern "C" void kernel_launch(void* const* d_in, const int* in_sizes, int n_in,
                              void* d_out, int out_size, void* d_ws, size_t ws_size,
                              hipStream_t stream) {
    const float* WPTR[12] = {
        (const float*)d_in[1], (const float*)d_in[2], (const float*)d_in[3],
        (const float*)d_in[4], (const float*)d_in[5], (const float*)d_in[6],
        (const float*)d_in[7], (const float*)d_in[8], (const float*)d_in[9],
        (const float*)d_in[10], (const float*)d_in[11], (const float*)d_in[12] };
    const float* vf    = (const float*)d_in[0];
    const float* gamma = (const float*)d_in[13];
    const float* beta  = (const float*)d_in[14];
    const int* c1 = (const int*)d_in[15];
    const int* c2 = (const int*)d_in[16];
    const int* c3 = (const int*)d_in[17];
    const int* c4 = (const int*)d_in[18];
    const int* c5 = (const int*)d_in[19];
    const int N1 = in_sizes[15] / 4;
    const int N2 = in_sizes[16] / 4;
    const int N3 = in_sizes[17] / 4;
    const int N4 = in_sizes[18] / 4;
    const int N5 = in_sizes[19] / 4;

    static const int LT[12]  = {27,27,27,27,27,27,27,27,27,27,27,3};
    static const int LCI[12] = {4,16,16,32,32,32,64,64,64,64,64,64};
    static const int LCO[12] = {16,16,32,32,32,64,64,64,64,64,64,128};

    const size_t G1 = (size_t)2*41*160*160;
    const size_t G2 = (size_t)2*21*80*80;
    const size_t G3 = (size_t)2*11*40*40;
    const size_t G4 = (size_t)2*5*20*20;
    int* grid1 = (int*)d_ws;
    int* grid2 = grid1 + G1;
    int* grid3 = grid2 + G2;
    int* grid4 = grid3 + G3;
    float* stats = (float*)(grid4 + G4);            // 12 x 256 floats

    size_t maxE = (size_t)N1*16;
    if ((size_t)N2*32  > maxE) maxE = (size_t)N2*32;
    if ((size_t)N3*64  > maxE) maxE = (size_t)N3*64;
    if ((size_t)N4*64  > maxE) maxE = (size_t)N4*64;
    if ((size_t)N5*128 > maxE) maxE = (size_t)N5*128;
    maxE = (maxE + 7) & ~(size_t)7;

    float* raw = stats + 12*256;                    // fp32 conv output
    unsigned short* fA = (unsigned short*)(raw + maxE);
    unsigned short* fB = fA + maxE;
    unsigned short* wtb = fB + maxE;                // bf16 transposed weights
    size_t wtoff[12];
    {
        size_t o = 0;
        for (int i = 1; i < 12; ++i) {
            wtoff[i] = o;
            o += (size_t)(LT[i] + 1) * LCI[i] * LCO[i];
        }
    }

    hipMemsetAsync(grid1, 0xFF, (G1+G2+G3+G4)*sizeof(int), stream);
    hipMemsetAsync(stats, 0, 12*256*sizeof(float), stream);

    {
        ScatterArgs sa;
        sa.coords[0]=c1; sa.coords[1]=c2; sa.coords[2]=c3; sa.coords[3]=c4;
        sa.grid[0]=grid1; sa.grid[1]=grid2; sa.grid[2]=grid3; sa.grid[3]=grid4;
        sa.n[0]=N1; sa.n[1]=N2; sa.n[2]=N3; sa.n[3]=N4;
        sa.D[0]=41; sa.H[0]=160; sa.W[0]=160;
        sa.D[1]=21; sa.H[1]= 80; sa.W[1]= 80;
        sa.D[2]=11; sa.H[2]= 40; sa.W[2]= 40;
        sa.D[3]= 5; sa.H[3]= 20; sa.W[3]= 20;
        int mx = N1; if (N2>mx) mx=N2; if (N3>mx) mx=N3; if (N4>mx) mx=N4;
        dim3 g((mx + 255)/256, 4);
        scatter_grid_all<<<g, 256, 0, stream>>>(sa);
    }
    {
        PrepArgs pa;
        int mx = 0;
        for (int i = 1; i < 12; ++i) {
            pa.src[i-1] = WPTR[i];
            pa.dst[i-1] = wtb + wtoff[i];
            pa.T[i-1] = LT[i]; pa.CIN[i-1] = LCI[i]; pa.COUT[i-1] = LCO[i];
            pa.total[i-1] = (LT[i]+1)*LCI[i]*LCO[i];
            if (pa.total[i-1] > mx) mx = pa.total[i-1];
        }
        dim3 g((mx + 255)/256, 11);
        prep_w_all<<<g, 256, 0, stream>>>(pa);
    }

    enum { GOFF_0 = 0, GOFF_1 = 16, GOFF_2 = 32, GOFF_3 = 64, GOFF_4 = 96, GOFF_5 = 128,
           GOFF_6 = 192, GOFF_7 = 256, GOFF_8 = 320, GOFF_9 = 384, GOFF_10 = 448, GOFF_11 = 512 };

#define APPLY(i, COUT, NP, FOUT_T, FOUT) \
    bn_relu_apply<COUT, FOUT_T><<<(((size_t)(NP)*(COUT)) + 255)/256, 256, 0, stream>>>( \
        raw, FOUT, NP, stats + (i)*256, gamma + GOFF_##i, beta + GOFF_##i);

    // L0: fp32 VALU conv + separate stats reduce
    sp_conv0<<<((size_t)N1*16 + 255)/256, 256, 0, stream>>>(vf, grid1, c1, N1, WPTR[0], raw, 41,160,160);
    { int rb = (N1 + 15)/16; if (rb > 240) rb = 240;
      reduce_stats<16><<<rb, 256, 0, stream>>>(raw, N1, stats + 0*256); }
    APPLY(0, 16, N1, unsigned short, fA);

#define CONV(i, CIN, COUT, KD,KH,KW, FIN, GRD, OC, NP, D,H,W, SZ,SY,SX, PZ,PY,PX) \
    sp_conv_mfma<CIN,COUT,KD,KH,KW><<<((NP)+63)/64, 256, 0, stream>>>( \
        FIN, GRD, OC, NP, wtb + wtoff[i], raw, stats + (i)*256, D,H,W, SZ,SY,SX, PZ,PY,PX);

    CONV( 1, 16, 16, 3,3,3, fA, grid1, c1, N1, 41,160,160, 1,1,1, 1,1,1); APPLY( 1, 16, N1, unsigned short, fB);
    CONV( 2, 16, 32, 3,3,3, fB, grid1, c2, N2, 41,160,160, 2,2,2, 1,1,1); APPLY( 2, 32, N2, unsigned short, fA);
    CONV( 3, 32, 32, 3,3,3, fA, grid2, c2, N2, 21, 80, 80, 1,1,1, 1,1,1); APPLY( 3, 32, N2, unsigned short, fB);
    CONV( 4, 32, 32, 3,3,3, fB, grid2, c2, N2, 21, 80, 80, 1,1,1, 1,1,1); APPLY( 4, 32, N2, unsigned short, fA);
    CONV( 5, 32, 64, 3,3,3, fA, grid2, c3, N3, 21, 80, 80, 2,2,2, 1,1,1); APPLY( 5, 64, N3, unsigned short, fB);
    CONV( 6, 64, 64, 3,3,3, fB, grid3, c3, N3, 11, 40, 40, 1,1,1, 1,1,1); APPLY( 6, 64, N3, unsigned short, fA);
    CONV( 7, 64, 64, 3,3,3, fA, grid3, c3, N3, 11, 40, 40, 1,1,1, 1,1,1); APPLY( 7, 64, N3, unsigned short, fB);
    CONV( 8, 64, 64, 3,3,3, fB, grid3, c4, N4, 11, 40, 40, 2,2,2, 0,1,1); APPLY( 8, 64, N4, unsigned short, fA);
    CONV( 9, 64, 64, 3,3,3, fA, grid4, c4, N4,  5, 20, 20, 1,1,1, 1,1,1); APPLY( 9, 64, N4, unsigned short, fB);
    CONV(10, 64, 64, 3,3,3, fB, grid4, c4, N4,  5, 20, 20, 1,1,1, 1,1,1); APPLY(10, 64, N4, unsigned short, fA);
    CONV(11, 64,128, 3,1,1, fA, grid4, c5, N5,  5, 20, 20, 2,1,1, 0,0,0); APPLY(11, 128, N5, float, (float*)d_out);
#undef CONV
#undef APPLY
}

// Round 6
// 618.257 us; speedup vs baseline: 1.0406x; 1.0406x over previous
//
#include <hip/hip_runtime.h>
#include <hip/hip_bf16.h>

// ---------------------------------------------------------------------------
// VoxelBackBone8x, R6: bf16 MFMA implicit-GEMM sparse conv, COUT-split waves.
// R5 lesson: heavy convs were TLP-starved, not ILP-starved — 546 blocks x 4
// waves = 8.5 waves/CU (2/SIMD); per-wave serial chain ~26k cyc had nothing
// to hide behind. R6: blockIdx.y = 16-cout tile (NT=1 per wave) -> 4x blocks,
// ~34 waves/CU for heavy layers, and 4x fewer B-loads per wave.
// Verified MFMA layouts (learn_hip m89/m91):
//   A[m=lane&15][k=quad*8+j], B[n=lane&15][k=quad*8+j],
//   C/D col=lane&15, row=quad*4+reg.
// ---------------------------------------------------------------------------

typedef __attribute__((ext_vector_type(8))) short bf16x8;
typedef __attribute__((ext_vector_type(4))) float f32x4;

__device__ inline unsigned short f2bf(float f) {
    unsigned u = __builtin_bit_cast(unsigned, f);
    u += 0x7FFFu + ((u >> 16) & 1u);
    return (unsigned short)(u >> 16);
}

struct ScatterArgs {
    const int* coords[4];
    int* grid[4];
    int n[4];
    int D[4], H[4], W[4];
};

__global__ __launch_bounds__(256) void scatter_grid_all(ScatterArgs a) {
    const int l = blockIdx.y;
    const int i = blockIdx.x * 256 + threadIdx.x;
    if (i >= a.n[l]) return;
    const int* c = a.coords[l] + 4 * i;
    a.grid[l][((c[0] * a.D[l] + c[1]) * a.H[l] + c[2]) * a.W[l] + c[3]] = i;
}

struct PrepArgs {
    const float* src[11];
    unsigned short* dst[11];
    int T[11], CIN[11], COUT[11], total[11];   // total = (T+1)*CIN*COUT
};

// fp32 [t][cin][cout] -> bf16 [t][cout][cin]; pad tap T zeroed
__global__ __launch_bounds__(256) void prep_w_all(PrepArgs a) {
    const int l = blockIdx.y;
    const int i = blockIdx.x * 256 + threadIdx.x;
    if (i >= a.total[l]) return;
    const int COUT = a.COUT[l], CIN = a.CIN[l], T = a.T[l];
    const int co = i % COUT; const int r = i / COUT; const int ci = r % CIN; const int t = r / CIN;
    unsigned short v = (t < T) ? f2bf(a.src[l][i]) : (unsigned short)0;
    a.dst[l][((size_t)t * COUT + co) * CIN + ci] = v;
}

// Layer 0: CIN=4 -> COUT=16, k=3, stride 1, pad 1, fp32 VALU
__global__ __launch_bounds__(256) void sp_conv0(const float* __restrict__ fin,
                                                const int* __restrict__ grid,
                                                const int* __restrict__ oc, int n_out,
                                                const float* __restrict__ w,
                                                float* __restrict__ out,
                                                int D, int H, int W) {
    const int c = threadIdx.x & 15;
    const int p = (blockIdx.x * 256 + threadIdx.x) >> 4;
    if (p >= n_out) return;
    const int b   = oc[4*p+0];
    const int iz0 = oc[4*p+1] - 1;
    const int iy0 = oc[4*p+2] - 1;
    const int ix0 = oc[4*p+3] - 1;
    const int* gb = grid + b * (D * H * W);
    float acc = 0.f;
    for (int kd = 0; kd < 3; ++kd) {
        const int iz = iz0 + kd;
        if ((unsigned)iz >= (unsigned)D) continue;
        for (int kh = 0; kh < 3; ++kh) {
            const int iy = iy0 + kh;
            if ((unsigned)iy >= (unsigned)H) continue;
            for (int kw = 0; kw < 3; ++kw) {
                const int ix = ix0 + kw;
                if ((unsigned)ix >= (unsigned)W) continue;
                const int idx = gb[(iz*H + iy)*W + ix];
                if (idx < 0) continue;
                const float4 v = *(const float4*)(fin + (size_t)idx * 4);
                const float* wp = w + (size_t)((kd*3 + kh)*3 + kw) * 4 * 16 + c;
                acc = fmaf(v.x, wp[0],  acc);
                acc = fmaf(v.y, wp[16], acc);
                acc = fmaf(v.z, wp[32], acc);
                acc = fmaf(v.w, wp[48], acc);
            }
        }
    }
    out[(size_t)p*16 + c] = acc;
}

// Wave = 16 points x 16 couts (one MFMA tile). blockIdx.y picks the cout tile.
template<int CIN, int COUT, int KD, int KH, int KW>
__global__ __launch_bounds__(256) void sp_conv_mfma(
    const unsigned short* __restrict__ fin, const int* __restrict__ grid,
    const int* __restrict__ oc, int n_out,
    const unsigned short* __restrict__ wt, float* __restrict__ out,
    float* __restrict__ stats,
    int D, int H, int W, int sz, int sy, int sx, int pz, int py, int px)
{
    constexpr int T = KD*KH*KW;
    __shared__ float ls[32];
    const int lane  = threadIdx.x & 63;
    const int wid   = threadIdx.x >> 6;
    const int n     = lane & 15;
    const int quad  = lane >> 4;
    const int ctile = blockIdx.y;                 // 16-cout tile
    const int cbase = ctile * 16;
    const int pbase = blockIdx.x * 64 + wid * 16;

    if (threadIdx.x < 32) ls[threadIdx.x] = 0.f;

    int pc = pbase + n;
    if (pc > n_out - 1) pc = n_out - 1;
    const int4 cc = ((const int4*)oc)[pc];
    const int* gb = grid + cc.x * (D * H * W);
    const int iz0 = cc.y * sz - pz;
    const int iy0 = cc.z * sy - py;
    const int ix0 = cc.w * sx - px;

    f32x4 acc = (f32x4){0.f, 0.f, 0.f, 0.f};

    if constexpr (CIN >= 32) {
        constexpr int S = CIN/32;
        constexpr int BATCH = (CIN >= 64) ? 7 : 14;
        int idx[T];
#pragma unroll
        for (int tap = 0; tap < T; ++tap) {
            const int kd = tap/(KH*KW), kr = tap%(KH*KW), kh = kr/KW, kw = kr%KW;
            const int iz = iz0 + kd, iy = iy0 + kh, ix = ix0 + kw;
            idx[tap] = ((unsigned)iz < (unsigned)D && (unsigned)iy < (unsigned)H &&
                        (unsigned)ix < (unsigned)W) ? gb[(iz*H + iy)*W + ix] : -1;
        }
#pragma unroll
        for (int t0 = 0; t0 < T; t0 += BATCH) {
            bf16x8 a[BATCH][S];
#pragma unroll
            for (int j = 0; j < BATCH; ++j) {
                const int tap = t0 + j;
                if (tap < T) {
#pragma unroll
                    for (int s = 0; s < S; ++s) {
                        a[j][s] = (bf16x8){};
                        if (idx[tap] >= 0)
                            a[j][s] = *(const bf16x8*)(fin + (size_t)idx[tap]*CIN + s*32 + quad*8);
                    }
                }
            }
#pragma unroll
            for (int j = 0; j < BATCH; ++j) {
                const int tap = t0 + j;
                if (tap < T) {
                    const unsigned short* wrow =
                        wt + ((size_t)tap*COUT + cbase + n)*CIN + quad*8;
#pragma unroll
                    for (int s = 0; s < S; ++s) {
                        bf16x8 b = *(const bf16x8*)(wrow + s*32);
                        acc = __builtin_amdgcn_mfma_f32_16x16x32_bf16(a[j][s], b, acc, 0, 0, 0);
                    }
                }
            }
        }
    } else {  // CIN == 16: 2 taps packed per K=32 (quad>>1 picks the tap)
        constexpr int KB = (T + 1) / 2;
        int idx[KB], tcv[KB];
        const int cinb = (quad & 1) * 8;
#pragma unroll
        for (int kb = 0; kb < KB; ++kb) {
            const int tap = 2*kb + (quad >> 1);
            const bool tv = (tap < T);
            const int td = tv ? tap : 0;
            const int kd = td/(KH*KW), kr = td%(KH*KW), kh = kr/KW, kw = kr%KW;
            const int iz = iz0 + kd, iy = iy0 + kh, ix = ix0 + kw;
            idx[kb] = (tv && (unsigned)iz < (unsigned)D && (unsigned)iy < (unsigned)H &&
                       (unsigned)ix < (unsigned)W) ? gb[(iz*H + iy)*W + ix] : -1;
            tcv[kb] = tv ? tap : T;   // pad slot zeroed by prep
        }
        bf16x8 a[KB];
#pragma unroll
        for (int kb = 0; kb < KB; ++kb) {
            a[kb] = (bf16x8){};
            if (idx[kb] >= 0) a[kb] = *(const bf16x8*)(fin + (size_t)idx[kb]*16 + cinb);
        }
#pragma unroll
        for (int kb = 0; kb < KB; ++kb) {
            bf16x8 b = *(const bf16x8*)(wt + ((size_t)tcv[kb]*COUT + cbase + n)*16 + cinb);
            acc = __builtin_amdgcn_mfma_f32_16x16x32_bf16(a[kb], b, acc, 0, 0, 0);
        }
    }

    // --- store raw fp32 (this block's 16-cout slice)
#pragma unroll
    for (int r = 0; r < 4; ++r) {
        const int p = pbase + quad*4 + r;
        if (p < n_out) out[(size_t)p * COUT + cbase + n] = acc[r];
    }

    // --- fused BN stats: quad shuffle-reduce -> LDS -> 1 atomic/ch/block
    __syncthreads();
    {
        float s1 = 0.f, s2 = 0.f;
#pragma unroll
        for (int r = 0; r < 4; ++r) {
            const int p = pbase + quad*4 + r;
            if (p < n_out) { const float v = acc[r]; s1 += v; s2 += v*v; }
        }
        s1 += __shfl_xor(s1, 16); s2 += __shfl_xor(s2, 16);
        s1 += __shfl_xor(s1, 32); s2 += __shfl_xor(s2, 32);
        if (quad == 0) {
            atomicAdd(&ls[n], s1);
            atomicAdd(&ls[16 + n], s2);
        }
    }
    __syncthreads();
    if (threadIdx.x < 16)
        atomicAdd(&stats[cbase + threadIdx.x], ls[threadIdx.x]);
    else if (threadIdx.x < 32)
        atomicAdd(&stats[COUT + cbase + (threadIdx.x - 16)], ls[threadIdx.x]);
}

template<int C>
__global__ __launch_bounds__(256) void reduce_stats(const float* __restrict__ x, int nn,
                                                    float* __restrict__ stats)
{
    constexpr int R = 256 / C;
    __shared__ float s1[256];
    __shared__ float s2[256];
    const int c = threadIdx.x % C;
    const int r = threadIdx.x / C;
    float a1 = 0.f, a2 = 0.f;
    for (int i = blockIdx.x * R + r; i < nn; i += R * gridDim.x) {
        float v = x[(size_t)i*C + c];
        a1 += v;
        a2 += v * v;
    }
    s1[threadIdx.x] = a1;
    s2[threadIdx.x] = a2;
    __syncthreads();
    for (int off = 128; off >= C; off >>= 1) {
        if (threadIdx.x < off) {
            s1[threadIdx.x] += s1[threadIdx.x + off];
            s2[threadIdx.x] += s2[threadIdx.x + off];
        }
        __syncthreads();
    }
    if (threadIdx.x < C) {
        atomicAdd(&stats[c],     s1[threadIdx.x]);
        atomicAdd(&stats[C + c], s2[threadIdx.x]);
    }
}

__device__ inline void stv(float* p, float v)          { *p = v; }
__device__ inline void stv(unsigned short* p, float v) { *p = f2bf(v); }

template<int C, typename OUT>
__global__ __launch_bounds__(256) void bn_relu_apply(const float* __restrict__ x,
                                                     OUT* __restrict__ y, int nn,
                                                     const float* __restrict__ stats,
                                                     const float* __restrict__ gamma,
                                                     const float* __restrict__ beta)
{
    const size_t i = (size_t)blockIdx.x * blockDim.x + threadIdx.x;
    if (i >= (size_t)nn * C) return;
    const int c = (int)(i % C);
    const float inv_n = 1.f / (float)nn;
    const float mu  = stats[c] * inv_n;
    const float var = stats[C + c] * inv_n - mu * mu;
    const float g = gamma[c] * rsqrtf(var + 1e-3f);
    const float v = (x[i] - mu) * g + beta[c];
    stv(y + i, v > 0.f ? v : 0.f);
}

extern "C" void kernel_launch(void* const* d_in, const int* in_sizes, int n_in,
                              void* d_out, int out_size, void* d_ws, size_t ws_size,
                              hipStream_t stream) {
    const float* WPTR[12] = {
        (const float*)d_in[1], (const float*)d_in[2], (const float*)d_in[3],
        (const float*)d_in[4], (const float*)d_in[5], (const float*)d_in[6],
        (const float*)d_in[7], (const float*)d_in[8], (const float*)d_in[9],
        (const float*)d_in[10], (const float*)d_in[11], (const float*)d_in[12] };
    const float* vf    = (const float*)d_in[0];
    const float* gamma = (const float*)d_in[13];
    const float* beta  = (const float*)d_in[14];
    const int* c1 = (const int*)d_in[15];
    const int* c2 = (const int*)d_in[16];
    const int* c3 = (const int*)d_in[17];
    const int* c4 = (const int*)d_in[18];
    const int* c5 = (const int*)d_in[19];
    const int N1 = in_sizes[15] / 4;
    const int N2 = in_sizes[16] / 4;
    const int N3 = in_sizes[17] / 4;
    const int N4 = in_sizes[18] / 4;
    const int N5 = in_sizes[19] / 4;

    static const int LT[12]  = {27,27,27,27,27,27,27,27,27,27,27,3};
    static const int LCI[12] = {4,16,16,32,32,32,64,64,64,64,64,64};
    static const int LCO[12] = {16,16,32,32,32,64,64,64,64,64,64,128};

    const size_t G1 = (size_t)2*41*160*160;
    const size_t G2 = (size_t)2*21*80*80;
    const size_t G3 = (size_t)2*11*40*40;
    const size_t G4 = (size_t)2*5*20*20;
    int* grid1 = (int*)d_ws;
    int* grid2 = grid1 + G1;
    int* grid3 = grid2 + G2;
    int* grid4 = grid3 + G3;
    float* stats = (float*)(grid4 + G4);            // 12 x 256 floats

    size_t maxE = (size_t)N1*16;
    if ((size_t)N2*32  > maxE) maxE = (size_t)N2*32;
    if ((size_t)N3*64  > maxE) maxE = (size_t)N3*64;
    if ((size_t)N4*64  > maxE) maxE = (size_t)N4*64;
    if ((size_t)N5*128 > maxE) maxE = (size_t)N5*128;
    maxE = (maxE + 7) & ~(size_t)7;

    float* raw = stats + 12*256;                    // fp32 conv output
    unsigned short* fA = (unsigned short*)(raw + maxE);
    unsigned short* fB = fA + maxE;
    unsigned short* wtb = fB + maxE;                // bf16 transposed weights
    size_t wtoff[12];
    {
        size_t o = 0;
        for (int i = 1; i < 12; ++i) {
            wtoff[i] = o;
            o += (size_t)(LT[i] + 1) * LCI[i] * LCO[i];
        }
    }

    hipMemsetAsync(grid1, 0xFF, (G1+G2+G3+G4)*sizeof(int), stream);
    hipMemsetAsync(stats, 0, 12*256*sizeof(float), stream);

    {
        ScatterArgs sa;
        sa.coords[0]=c1; sa.coords[1]=c2; sa.coords[2]=c3; sa.coords[3]=c4;
        sa.grid[0]=grid1; sa.grid[1]=grid2; sa.grid[2]=grid3; sa.grid[3]=grid4;
        sa.n[0]=N1; sa.n[1]=N2; sa.n[2]=N3; sa.n[3]=N4;
        sa.D[0]=41; sa.H[0]=160; sa.W[0]=160;
        sa.D[1]=21; sa.H[1]= 80; sa.W[1]= 80;
        sa.D[2]=11; sa.H[2]= 40; sa.W[2]= 40;
        sa.D[3]= 5; sa.H[3]= 20; sa.W[3]= 20;
        int mx = N1; if (N2>mx) mx=N2; if (N3>mx) mx=N3; if (N4>mx) mx=N4;
        dim3 g((mx + 255)/256, 4);
        scatter_grid_all<<<g, 256, 0, stream>>>(sa);
    }
    {
        PrepArgs pa;
        int mx = 0;
        for (int i = 1; i < 12; ++i) {
            pa.src[i-1] = WPTR[i];
            pa.dst[i-1] = wtb + wtoff[i];
            pa.T[i-1] = LT[i]; pa.CIN[i-1] = LCI[i]; pa.COUT[i-1] = LCO[i];
            pa.total[i-1] = (LT[i]+1)*LCI[i]*LCO[i];
            if (pa.total[i-1] > mx) mx = pa.total[i-1];
        }
        dim3 g((mx + 255)/256, 11);
        prep_w_all<<<g, 256, 0, stream>>>(pa);
    }

    enum { GOFF_0 = 0, GOFF_1 = 16, GOFF_2 = 32, GOFF_3 = 64, GOFF_4 = 96, GOFF_5 = 128,
           GOFF_6 = 192, GOFF_7 = 256, GOFF_8 = 320, GOFF_9 = 384, GOFF_10 = 448, GOFF_11 = 512 };

#define APPLY(i, COUT, NP, FOUT_T, FOUT) \
    bn_relu_apply<COUT, FOUT_T><<<(((size_t)(NP)*(COUT)) + 255)/256, 256, 0, stream>>>( \
        raw, FOUT, NP, stats + (i)*256, gamma + GOFF_##i, beta + GOFF_##i);

    // L0: fp32 VALU conv + separate stats reduce
    sp_conv0<<<((size_t)N1*16 + 255)/256, 256, 0, stream>>>(vf, grid1, c1, N1, WPTR[0], raw, 41,160,160);
    { int rb = (N1 + 15)/16; if (rb > 240) rb = 240;
      reduce_stats<16><<<rb, 256, 0, stream>>>(raw, N1, stats + 0*256); }
    APPLY(0, 16, N1, unsigned short, fA);

#define CONV(i, CIN, COUT, KD,KH,KW, FIN, GRD, OC, NP, D,H,W, SZ,SY,SX, PZ,PY,PX) \
    { dim3 g_(((NP)+63)/64, (COUT)/16); \
      sp_conv_mfma<CIN,COUT,KD,KH,KW><<<g_, 256, 0, stream>>>( \
          FIN, GRD, OC, NP, wtb + wtoff[i], raw, stats + (i)*256, D,H,W, SZ,SY,SX, PZ,PY,PX); }

    CONV( 1, 16, 16, 3,3,3, fA, grid1, c1, N1, 41,160,160, 1,1,1, 1,1,1); APPLY( 1, 16, N1, unsigned short, fB);
    CONV( 2, 16, 32, 3,3,3, fB, grid1, c2, N2, 41,160,160, 2,2,2, 1,1,1); APPLY( 2, 32, N2, unsigned short, fA);
    CONV( 3, 32, 32, 3,3,3, fA, grid2, c2, N2, 21, 80, 80, 1,1,1, 1,1,1); APPLY( 3, 32, N2, unsigned short, fB);
    CONV( 4, 32, 32, 3,3,3, fB, grid2, c2, N2, 21, 80, 80, 1,1,1, 1,1,1); APPLY( 4, 32, N2, unsigned short, fA);
    CONV( 5, 32, 64, 3,3,3, fA, grid2, c3, N3, 21, 80, 80, 2,2,2, 1,1,1); APPLY( 5, 64, N3, unsigned short, fB);
    CONV( 6, 64, 64, 3,3,3, fB, grid3, c3, N3, 11, 40, 40, 1,1,1, 1,1,1); APPLY( 6, 64, N3, unsigned short, fA);
    CONV( 7, 64, 64, 3,3,3, fA, grid3, c3, N3, 11, 40, 40, 1,1,1, 1,1,1); APPLY( 7, 64, N3, unsigned short, fB);
    CONV( 8, 64, 64, 3,3,3, fB, grid3, c4, N4, 11, 40, 40, 2,2,2, 0,1,1); APPLY( 8, 64, N4, unsigned short, fA);
    CONV( 9, 64, 64, 3,3,3, fA, grid4, c4, N4,  5, 20, 20, 1,1,1, 1,1,1); APPLY( 9, 64, N4, unsigned short, fB);
    CONV(10, 64, 64, 3,3,3, fB, grid4, c4, N4,  5, 20, 20, 1,1,1, 1,1,1); APPLY(10, 64, N4, unsigned short, fA);
    CONV(11, 64,128, 3,1,1, fA, grid4, c5, N5,  5, 20, 20, 2,1,1, 0,0,0); APPLY(11, 128, N5, float, (float*)d_out);
#undef CONV
#undef APPLY
}

// Round 7
// 612.324 us; speedup vs baseline: 1.0507x; 1.0097x over previous
//
#include <hip/hip_runtime.h>
#include <hip/hip_bf16.h>

// ---------------------------------------------------------------------------
// VoxelBackBone8x, R7: branchless batched-load MFMA sparse conv.
// R6 lesson: per-load `if (idx>=0)` exec-mask branches serialized ~110 VMEM
// loads per wave at ~700cyc each (74k cyc/wave measured). R7: zero-row pad
// before feature buffers makes A-loads unconditional (idx=-1 reads zeros);
// taps padded to BATCH multiples (weight pad slot zeroed); per round, A and B
// loads all issued before any use; launch_bounds(256,4) keeps VGPR<=128.
// Verified MFMA layouts (learn_hip m89/m91):
//   A[m=lane&15][k=quad*8+j], B[n=lane&15][k=quad*8+j],
//   C/D col=lane&15, row=quad*4+reg.
// ---------------------------------------------------------------------------

typedef __attribute__((ext_vector_type(8))) short bf16x8;
typedef __attribute__((ext_vector_type(4))) short bf16x4s;
typedef __attribute__((ext_vector_type(4))) float f32x4;

__device__ inline unsigned short f2bf(float f) {
    unsigned u = __builtin_bit_cast(unsigned, f);
    u += 0x7FFFu + ((u >> 16) & 1u);
    return (unsigned short)(u >> 16);
}

struct ScatterArgs {
    const int* coords[4];
    int* grid[4];
    int n[4];
    int D[4], H[4], W[4];
};

__global__ __launch_bounds__(256) void scatter_grid_all(ScatterArgs a) {
    const int l = blockIdx.y;
    const int i = blockIdx.x * 256 + threadIdx.x;
    if (i >= a.n[l]) return;
    const int* c = a.coords[l] + 4 * i;
    a.grid[l][((c[0] * a.D[l] + c[1]) * a.H[l] + c[2]) * a.W[l] + c[3]] = i;
}

struct PrepArgs {
    const float* src[11];
    unsigned short* dst[11];
    int T[11], CIN[11], COUT[11], total[11];   // total = (T+1)*CIN*COUT
};

// fp32 [t][cin][cout] -> bf16 [t][cout][cin]; pad tap T zeroed
__global__ __launch_bounds__(256) void prep_w_all(PrepArgs a) {
    const int l = blockIdx.y;
    const int i = blockIdx.x * 256 + threadIdx.x;
    if (i >= a.total[l]) return;
    const int COUT = a.COUT[l], CIN = a.CIN[l], T = a.T[l];
    const int co = i % COUT; const int r = i / COUT; const int ci = r % CIN; const int t = r / CIN;
    unsigned short v = (t < T) ? f2bf(a.src[l][i]) : (unsigned short)0;
    a.dst[l][((size_t)t * COUT + co) * CIN + ci] = v;
}

// Layer 0: CIN=4 -> COUT=16, branchless batched loads
__global__ __launch_bounds__(256, 4) void sp_conv0(const float* __restrict__ fin,
                                                   const int* __restrict__ grid,
                                                   const int* __restrict__ oc, int n_out,
                                                   const float* __restrict__ w,
                                                   float* __restrict__ out,
                                                   int D, int H, int W) {
    const int c = threadIdx.x & 15;
    const int p = (blockIdx.x * 256 + threadIdx.x) >> 4;
    if (p >= n_out) return;
    const int b   = oc[4*p+0];
    const int iz0 = oc[4*p+1] - 1;
    const int iy0 = oc[4*p+2] - 1;
    const int ix0 = oc[4*p+3] - 1;
    const int* gb = grid + b * (D * H * W);
    int idx[27];
#pragma unroll
    for (int tap = 0; tap < 27; ++tap) {
        const int kd = tap/9, kr = tap%9, kh = kr/3, kw = kr%3;
        const int iz = iz0 + kd, iy = iy0 + kh, ix = ix0 + kw;
        const bool ok = (unsigned)iz < (unsigned)D && (unsigned)iy < (unsigned)H &&
                        (unsigned)ix < (unsigned)W;
        const int cz = iz < 0 ? 0 : (iz >= D ? D-1 : iz);
        const int cy = iy < 0 ? 0 : (iy >= H ? H-1 : iy);
        const int cx = ix < 0 ? 0 : (ix >= W ? W-1 : ix);
        const int g = gb[(cz*H + cy)*W + cx];
        idx[tap] = ok ? g : -1;
    }
    float acc = 0.f;
#pragma unroll
    for (int tap = 0; tap < 27; ++tap) {
        const int   id = idx[tap] < 0 ? 0 : idx[tap];
        const float m  = idx[tap] < 0 ? 0.f : 1.f;
        const float4 v = *(const float4*)(fin + (size_t)id * 4);
        const float* wp = w + (size_t)tap * 64 + c;
        float t = v.x*wp[0] + v.y*wp[16] + v.z*wp[32] + v.w*wp[48];
        acc = fmaf(m, t, acc);
    }
    out[(size_t)p*16 + c] = acc;
}

// Wave = 16 points x 16 couts; blockIdx.y = cout tile.
template<int CIN, int COUT, int KD, int KH, int KW>
__global__ __launch_bounds__(256, 4) void sp_conv_mfma(
    const unsigned short* __restrict__ fin, const int* __restrict__ grid,
    const int* __restrict__ oc, int n_out,
    const unsigned short* __restrict__ wt, float* __restrict__ out,
    float* __restrict__ stats,
    int D, int H, int W, int sz, int sy, int sx, int pz, int py, int px)
{
    constexpr int T = KD*KH*KW;
    __shared__ float ls[32];
    const int lane  = threadIdx.x & 63;
    const int wid   = threadIdx.x >> 6;
    const int n     = lane & 15;
    const int quad  = lane >> 4;
    const int cbase = blockIdx.y * 16;
    const int pbase = blockIdx.x * 64 + wid * 16;

    if (threadIdx.x < 32) ls[threadIdx.x] = 0.f;

    int pc = pbase + n;
    if (pc > n_out - 1) pc = n_out - 1;
    const int4 cc = ((const int4*)oc)[pc];
    const int* gb = grid + cc.x * (D * H * W);
    const int iz0 = cc.y * sz - pz;
    const int iy0 = cc.z * sy - py;
    const int ix0 = cc.w * sx - px;

    f32x4 acc = (f32x4){0.f, 0.f, 0.f, 0.f};

    if constexpr (CIN >= 32) {
        constexpr int S = CIN/32;
        constexpr int BATCH = (CIN >= 64) ? 4 : 7;
        constexpr int TP = ((T + BATCH - 1)/BATCH)*BATCH;   // 28 (T=27), 4 (T=3)
        int idx[TP];
#pragma unroll
        for (int tap = 0; tap < TP; ++tap) {
            const int te = tap < T ? tap : 0;
            const int kd = te/(KH*KW), kr = te%(KH*KW), kh = kr/KW, kw = kr%KW;
            const int iz = iz0 + kd, iy = iy0 + kh, ix = ix0 + kw;
            const bool ok = (tap < T) && (unsigned)iz < (unsigned)D &&
                            (unsigned)iy < (unsigned)H && (unsigned)ix < (unsigned)W;
            const int cz = iz < 0 ? 0 : (iz >= D ? D-1 : iz);
            const int cy = iy < 0 ? 0 : (iy >= H ? H-1 : iy);
            const int cx = ix < 0 ? 0 : (ix >= W ? W-1 : ix);
            const int g = gb[(cz*H + cy)*W + cx];
            idx[tap] = ok ? g : -1;     // -1 -> zero pad row before fin
        }
#pragma unroll
        for (int t0 = 0; t0 < TP; t0 += BATCH) {
            bf16x8 a[BATCH][S], b[BATCH][S];
#pragma unroll
            for (int j = 0; j < BATCH; ++j)
#pragma unroll
                for (int s = 0; s < S; ++s)
                    a[j][s] = *(const bf16x8*)(fin + (ptrdiff_t)idx[t0+j]*CIN + s*32 + quad*8);
#pragma unroll
            for (int j = 0; j < BATCH; ++j) {
                const int tw = (t0+j) < T ? (t0+j) : T;     // pad slot zeroed
#pragma unroll
                for (int s = 0; s < S; ++s)
                    b[j][s] = *(const bf16x8*)(wt + ((size_t)tw*COUT + cbase + n)*CIN + s*32 + quad*8);
            }
#pragma unroll
            for (int j = 0; j < BATCH; ++j)
#pragma unroll
                for (int s = 0; s < S; ++s)
                    acc = __builtin_amdgcn_mfma_f32_16x16x32_bf16(a[j][s], b[j][s], acc, 0, 0, 0);
        }
    } else {  // CIN == 16: 2 taps per K=32 (quad>>1 picks tap); KB=14 exact
        constexpr int KB = (T + 1) / 2;
        constexpr int BATCH = 7;
        const int cinb = (quad & 1) * 8;
        int idx[KB];
#pragma unroll
        for (int kb = 0; kb < KB; ++kb) {
            const int tap = 2*kb + (quad >> 1);
            const int te = tap < T ? tap : 0;
            const int kd = te/(KH*KW), kr = te%(KH*KW), kh = kr/KW, kw = kr%KW;
            const int iz = iz0 + kd, iy = iy0 + kh, ix = ix0 + kw;
            const bool ok = (tap < T) && (unsigned)iz < (unsigned)D &&
                            (unsigned)iy < (unsigned)H && (unsigned)ix < (unsigned)W;
            const int cz = iz < 0 ? 0 : (iz >= D ? D-1 : iz);
            const int cy = iy < 0 ? 0 : (iy >= H ? H-1 : iy);
            const int cx = ix < 0 ? 0 : (ix >= W ? W-1 : ix);
            const int g = gb[(cz*H + cy)*W + cx];
            idx[kb] = ok ? g : -1;
        }
#pragma unroll
        for (int k0 = 0; k0 < KB; k0 += BATCH) {
            bf16x8 a[BATCH], b[BATCH];
#pragma unroll
            for (int j = 0; j < BATCH; ++j)
                a[j] = *(const bf16x8*)(fin + (ptrdiff_t)idx[k0+j]*16 + cinb);
#pragma unroll
            for (int j = 0; j < BATCH; ++j) {
                const int tap = 2*(k0+j) + (quad >> 1);
                const int tw = tap < T ? tap : T;
                b[j] = *(const bf16x8*)(wt + ((size_t)tw*COUT + cbase + n)*16 + cinb);
            }
#pragma unroll
            for (int j = 0; j < BATCH; ++j)
                acc = __builtin_amdgcn_mfma_f32_16x16x32_bf16(a[j], b[j], acc, 0, 0, 0);
        }
    }

    // --- store raw fp32 (this block's 16-cout slice)
#pragma unroll
    for (int r = 0; r < 4; ++r) {
        const int p = pbase + quad*4 + r;
        if (p < n_out) out[(size_t)p * COUT + cbase + n] = acc[r];
    }

    // --- fused BN stats
    __syncthreads();
    {
        float s1 = 0.f, s2 = 0.f;
#pragma unroll
        for (int r = 0; r < 4; ++r) {
            const int p = pbase + quad*4 + r;
            if (p < n_out) { const float v = acc[r]; s1 += v; s2 += v*v; }
        }
        s1 += __shfl_xor(s1, 16); s2 += __shfl_xor(s2, 16);
        s1 += __shfl_xor(s1, 32); s2 += __shfl_xor(s2, 32);
        if (quad == 0) {
            atomicAdd(&ls[n], s1);
            atomicAdd(&ls[16 + n], s2);
        }
    }
    __syncthreads();
    if (threadIdx.x < 16)
        atomicAdd(&stats[cbase + threadIdx.x], ls[threadIdx.x]);
    else if (threadIdx.x < 32)
        atomicAdd(&stats[COUT + cbase + (threadIdx.x - 16)], ls[threadIdx.x]);
}

template<int C>
__global__ __launch_bounds__(256) void reduce_stats(const float* __restrict__ x, int nn,
                                                    float* __restrict__ stats)
{
    constexpr int R = 256 / C;
    __shared__ float s1[256];
    __shared__ float s2[256];
    const int c = threadIdx.x % C;
    const int r = threadIdx.x / C;
    float a1 = 0.f, a2 = 0.f;
    for (int i = blockIdx.x * R + r; i < nn; i += R * gridDim.x) {
        float v = x[(size_t)i*C + c];
        a1 += v;
        a2 += v * v;
    }
    s1[threadIdx.x] = a1;
    s2[threadIdx.x] = a2;
    __syncthreads();
    for (int off = 128; off >= C; off >>= 1) {
        if (threadIdx.x < off) {
            s1[threadIdx.x] += s1[threadIdx.x + off];
            s2[threadIdx.x] += s2[threadIdx.x + off];
        }
        __syncthreads();
    }
    if (threadIdx.x < C) {
        atomicAdd(&stats[c],     s1[threadIdx.x]);
        atomicAdd(&stats[C + c], s2[threadIdx.x]);
    }
}

__device__ inline void stv4(float* p, float4 v) { *(float4*)p = v; }
__device__ inline void stv4(unsigned short* p, float4 v) {
    bf16x4s o;
    o.x = (short)f2bf(v.x); o.y = (short)f2bf(v.y);
    o.z = (short)f2bf(v.z); o.w = (short)f2bf(v.w);
    *(bf16x4s*)p = o;
}

// 4 channels per thread, vectorized
template<int C, typename OUT>
__global__ __launch_bounds__(256) void bn_relu_apply(const float* __restrict__ x,
                                                     OUT* __restrict__ y, int nn,
                                                     const float* __restrict__ stats,
                                                     const float* __restrict__ gamma,
                                                     const float* __restrict__ beta)
{
    const size_t q = (size_t)blockIdx.x * blockDim.x + threadIdx.x;
    if (q >= (size_t)nn * (C/4)) return;
    const int c = (int)(q % (size_t)(C/4)) * 4;
    const float inv_n = 1.f / (float)nn;
    const float4 xv = *(const float4*)(x + q*4);
    const float4 s1 = *(const float4*)(stats + c);
    const float4 s2 = *(const float4*)(stats + C + c);
    const float4 gm = *(const float4*)(gamma + c);
    const float4 bt = *(const float4*)(beta + c);
    float4 o;
    {
        float mu = s1.x*inv_n, var = s2.x*inv_n - mu*mu, g = gm.x*rsqrtf(var+1e-3f);
        float v = (xv.x - mu)*g + bt.x; o.x = v > 0.f ? v : 0.f;
    }
    {
        float mu = s1.y*inv_n, var = s2.y*inv_n - mu*mu, g = gm.y*rsqrtf(var+1e-3f);
        float v = (xv.y - mu)*g + bt.y; o.y = v > 0.f ? v : 0.f;
    }
    {
        float mu = s1.z*inv_n, var = s2.z*inv_n - mu*mu, g = gm.z*rsqrtf(var+1e-3f);
        float v = (xv.z - mu)*g + bt.z; o.z = v > 0.f ? v : 0.f;
    }
    {
        float mu = s1.w*inv_n, var = s2.w*inv_n - mu*mu, g = gm.w*rsqrtf(var+1e-3f);
        float v = (xv.w - mu)*g + bt.w; o.w = v > 0.f ? v : 0.f;
    }
    stv4(y + q*4, o);
}

extern "C" void kernel_launch(void* const* d_in, const int* in_sizes, int n_in,
                              void* d_out, int out_size, void* d_ws, size_t ws_size,
                              hipStream_t stream) {
    const float* WPTR[12] = {
        (const float*)d_in[1], (const float*)d_in[2], (const float*)d_in[3],
        (const float*)d_in[4], (const float*)d_in[5], (const float*)d_in[6],
        (const float*)d_in[7], (const float*)d_in[8], (const float*)d_in[9],
        (const float*)d_in[10], (const float*)d_in[11], (const float*)d_in[12] };
    const float* vf    = (const float*)d_in[0];
    const float* gamma = (const float*)d_in[13];
    const float* beta  = (const float*)d_in[14];
    const int* c1 = (const int*)d_in[15];
    const int* c2 = (const int*)d_in[16];
    const int* c3 = (const int*)d_in[17];
    const int* c4 = (const int*)d_in[18];
    const int* c5 = (const int*)d_in[19];
    const int N1 = in_sizes[15] / 4;
    const int N2 = in_sizes[16] / 4;
    const int N3 = in_sizes[17] / 4;
    const int N4 = in_sizes[18] / 4;
    const int N5 = in_sizes[19] / 4;

    static const int LT[12]  = {27,27,27,27,27,27,27,27,27,27,27,3};
    static const int LCI[12] = {4,16,16,32,32,32,64,64,64,64,64,64};
    static const int LCO[12] = {16,16,32,32,32,64,64,64,64,64,64,128};

    const size_t G1 = (size_t)2*41*160*160;
    const size_t G2 = (size_t)2*21*80*80;
    const size_t G3 = (size_t)2*11*40*40;
    const size_t G4 = (size_t)2*5*20*20;
    int* grid1 = (int*)d_ws;
    int* grid2 = grid1 + G1;
    int* grid3 = grid2 + G2;
    int* grid4 = grid3 + G3;
    float* stats = (float*)(grid4 + G4);            // 12 x 256 floats

    size_t maxE = (size_t)N1*16;
    if ((size_t)N2*32  > maxE) maxE = (size_t)N2*32;
    if ((size_t)N3*64  > maxE) maxE = (size_t)N3*64;
    if ((size_t)N4*64  > maxE) maxE = (size_t)N4*64;
    if ((size_t)N5*128 > maxE) maxE = (size_t)N5*128;
    maxE = (maxE + 7) & ~(size_t)7;

    float* raw = stats + 12*256;                    // fp32 conv output
    unsigned short* padA = (unsigned short*)(raw + maxE);
    unsigned short* fA   = padA + 128;              // zero row lives at fA-CIN
    unsigned short* padB = fA + maxE;
    unsigned short* fB   = padB + 128;
    unsigned short* wtb  = fB + maxE;               // bf16 transposed weights
    size_t wtoff[12];
    {
        size_t o = 0;
        for (int i = 1; i < 12; ++i) {
            wtoff[i] = o;
            o += (size_t)(LT[i] + 1) * LCI[i] * LCO[i];
        }
    }

    hipMemsetAsync(grid1, 0xFF, (G1+G2+G3+G4)*sizeof(int), stream);
    hipMemsetAsync(stats, 0, 12*256*sizeof(float), stream);
    hipMemsetAsync(padA, 0, 128*sizeof(unsigned short), stream);
    hipMemsetAsync(padB, 0, 128*sizeof(unsigned short), stream);

    {
        ScatterArgs sa;
        sa.coords[0]=c1; sa.coords[1]=c2; sa.coords[2]=c3; sa.coords[3]=c4;
        sa.grid[0]=grid1; sa.grid[1]=grid2; sa.grid[2]=grid3; sa.grid[3]=grid4;
        sa.n[0]=N1; sa.n[1]=N2; sa.n[2]=N3; sa.n[3]=N4;
        sa.D[0]=41; sa.H[0]=160; sa.W[0]=160;
        sa.D[1]=21; sa.H[1]= 80; sa.W[1]= 80;
        sa.D[2]=11; sa.H[2]= 40; sa.W[2]= 40;
        sa.D[3]= 5; sa.H[3]= 20; sa.W[3]= 20;
        int mx = N1; if (N2>mx) mx=N2; if (N3>mx) mx=N3; if (N4>mx) mx=N4;
        dim3 g((mx + 255)/256, 4);
        scatter_grid_all<<<g, 256, 0, stream>>>(sa);
    }
    {
        PrepArgs pa;
        int mx = 0;
        for (int i = 1; i < 12; ++i) {
            pa.src[i-1] = WPTR[i];
            pa.dst[i-1] = wtb + wtoff[i];
            pa.T[i-1] = LT[i]; pa.CIN[i-1] = LCI[i]; pa.COUT[i-1] = LCO[i];
            pa.total[i-1] = (LT[i]+1)*LCI[i]*LCO[i];
            if (pa.total[i-1] > mx) mx = pa.total[i-1];
        }
        dim3 g((mx + 255)/256, 11);
        prep_w_all<<<g, 256, 0, stream>>>(pa);
    }

    enum { GOFF_0 = 0, GOFF_1 = 16, GOFF_2 = 32, GOFF_3 = 64, GOFF_4 = 96, GOFF_5 = 128,
           GOFF_6 = 192, GOFF_7 = 256, GOFF_8 = 320, GOFF_9 = 384, GOFF_10 = 448, GOFF_11 = 512 };

#define APPLY(i, COUT, NP, FOUT_T, FOUT) \
    bn_relu_apply<COUT, FOUT_T><<<(((size_t)(NP)*(COUT)/4) + 255)/256, 256, 0, stream>>>( \
        raw, FOUT, NP, stats + (i)*256, gamma + GOFF_##i, beta + GOFF_##i);

    // L0: fp32 VALU conv + separate stats reduce
    sp_conv0<<<((size_t)N1*16 + 255)/256, 256, 0, stream>>>(vf, grid1, c1, N1, WPTR[0], raw, 41,160,160);
    { int rb = (N1 + 15)/16; if (rb > 240) rb = 240;
      reduce_stats<16><<<rb, 256, 0, stream>>>(raw, N1, stats + 0*256); }
    APPLY(0, 16, N1, unsigned short, fA);

#define CONV(i, CIN, COUT, KD,KH,KW, FIN, GRD, OC, NP, D,H,W, SZ,SY,SX, PZ,PY,PX) \
    { dim3 g_(((NP)+63)/64, (COUT)/16); \
      sp_conv_mfma<CIN,COUT,KD,KH,KW><<<g_, 256, 0, stream>>>( \
          FIN, GRD, OC, NP, wtb + wtoff[i], raw, stats + (i)*256, D,H,W, SZ,SY,SX, PZ,PY,PX); }

    CONV( 1, 16, 16, 3,3,3, fA, grid1, c1, N1, 41,160,160, 1,1,1, 1,1,1); APPLY( 1, 16, N1, unsigned short, fB);
    CONV( 2, 16, 32, 3,3,3, fB, grid1, c2, N2, 41,160,160, 2,2,2, 1,1,1); APPLY( 2, 32, N2, unsigned short, fA);
    CONV( 3, 32, 32, 3,3,3, fA, grid2, c2, N2, 21, 80, 80, 1,1,1, 1,1,1); APPLY( 3, 32, N2, unsigned short, fB);
    CONV( 4, 32, 32, 3,3,3, fB, grid2, c2, N2, 21, 80, 80, 1,1,1, 1,1,1); APPLY( 4, 32, N2, unsigned short, fA);
    CONV( 5, 32, 64, 3,3,3, fA, grid2, c3, N3, 21, 80, 80, 2,2,2, 1,1,1); APPLY( 5, 64, N3, unsigned short, fB);
    CONV( 6, 64, 64, 3,3,3, fB, grid3, c3, N3, 11, 40, 40, 1,1,1, 1,1,1); APPLY( 6, 64, N3, unsigned short, fA);
    CONV( 7, 64, 64, 3,3,3, fA, grid3, c3, N3, 11, 40, 40, 1,1,1, 1,1,1); APPLY( 7, 64, N3, unsigned short, fB);
    CONV( 8, 64, 64, 3,3,3, fB, grid3, c4, N4, 11, 40, 40, 2,2,2, 0,1,1); APPLY( 8, 64, N4, unsigned short, fA);
    CONV( 9, 64, 64, 3,3,3, fA, grid4, c4, N4,  5, 20, 20, 1,1,1, 1,1,1); APPLY( 9, 64, N4, unsigned short, fB);
    CONV(10, 64, 64, 3,3,3, fB, grid4, c4, N4,  5, 20, 20, 1,1,1, 1,1,1); APPLY(10, 64, N4, unsigned short, fA);
    CONV(11, 64,128, 3,1,1, fA, grid4, c5, N5,  5, 20, 20, 2,1,1, 0,0,0); APPLY(11, 128, N5, float, (float*)d_out);
#undef CONV
#undef APPLY
}

// Round 8
// 607.411 us; speedup vs baseline: 1.0592x; 1.0081x over previous
//
#include <hip/hip_runtime.h>
#include <hip/hip_bf16.h>

// ---------------------------------------------------------------------------
// VoxelBackBone8x, R8: MFMA sparse conv with sched_barrier-pinned load batches.
// R7 lesson: VGPR_Count=40 proved the compiler rolled the load batches back
// into load->use chains (1 outstanding load/wave, ~123k cyc/wave = 112 loads
// x ~900cyc serial). R8 pins each batch with __builtin_amdgcn_sched_barrier(0)
// after the load cluster: loads get distinct live registers and stay in
// flight together (1 latency round per batch, ~8 rounds/wave total).
// Verified MFMA layouts (learn_hip m89/m91):
//   A[m=lane&15][k=quad*8+j], B[n=lane&15][k=quad*8+j],
//   C/D col=lane&15, row=quad*4+reg.
// ---------------------------------------------------------------------------

typedef __attribute__((ext_vector_type(8))) short bf16x8;
typedef __attribute__((ext_vector_type(4))) short bf16x4s;
typedef __attribute__((ext_vector_type(4))) float f32x4;

__device__ inline unsigned short f2bf(float f) {
    unsigned u = __builtin_bit_cast(unsigned, f);
    u += 0x7FFFu + ((u >> 16) & 1u);
    return (unsigned short)(u >> 16);
}

struct ScatterArgs {
    const int* coords[4];
    int* grid[4];
    int n[4];
    int D[4], H[4], W[4];
};

__global__ __launch_bounds__(256) void scatter_grid_all(ScatterArgs a) {
    const int l = blockIdx.y;
    const int i = blockIdx.x * 256 + threadIdx.x;
    if (i >= a.n[l]) return;
    const int* c = a.coords[l] + 4 * i;
    a.grid[l][((c[0] * a.D[l] + c[1]) * a.H[l] + c[2]) * a.W[l] + c[3]] = i;
}

struct PrepArgs {
    const float* src[11];
    unsigned short* dst[11];
    int T[11], CIN[11], COUT[11], total[11];   // total = (T+1)*CIN*COUT
};

// fp32 [t][cin][cout] -> bf16 [t][cout][cin]; pad tap T zeroed
__global__ __launch_bounds__(256) void prep_w_all(PrepArgs a) {
    const int l = blockIdx.y;
    const int i = blockIdx.x * 256 + threadIdx.x;
    if (i >= a.total[l]) return;
    const int COUT = a.COUT[l], CIN = a.CIN[l], T = a.T[l];
    const int co = i % COUT; const int r = i / COUT; const int ci = r % CIN; const int t = r / CIN;
    unsigned short v = (t < T) ? f2bf(a.src[l][i]) : (unsigned short)0;
    a.dst[l][((size_t)t * COUT + co) * CIN + ci] = v;
}

// Layer 0: CIN=4 -> COUT=16
__global__ __launch_bounds__(256, 4) void sp_conv0(const float* __restrict__ fin,
                                                   const int* __restrict__ grid,
                                                   const int* __restrict__ oc, int n_out,
                                                   const float* __restrict__ w,
                                                   float* __restrict__ out,
                                                   int D, int H, int W) {
    const int c = threadIdx.x & 15;
    const int p = (blockIdx.x * 256 + threadIdx.x) >> 4;
    if (p >= n_out) return;
    const int b   = oc[4*p+0];
    const int iz0 = oc[4*p+1] - 1;
    const int iy0 = oc[4*p+2] - 1;
    const int ix0 = oc[4*p+3] - 1;
    const int* gb = grid + b * (D * H * W);
    int g[27];
    unsigned okm = 0;
#pragma unroll
    for (int tap = 0; tap < 27; ++tap) {
        const int kd = tap/9, kr = tap%9, kh = kr/3, kw = kr%3;
        const int iz = iz0 + kd, iy = iy0 + kh, ix = ix0 + kw;
        const bool ok = (unsigned)iz < (unsigned)D && (unsigned)iy < (unsigned)H &&
                        (unsigned)ix < (unsigned)W;
        okm |= (unsigned)ok << tap;
        const int cz = iz < 0 ? 0 : (iz >= D ? D-1 : iz);
        const int cy = iy < 0 ? 0 : (iy >= H ? H-1 : iy);
        const int cx = ix < 0 ? 0 : (ix >= W ? W-1 : ix);
        g[tap] = gb[(cz*H + cy)*W + cx];
    }
    __builtin_amdgcn_sched_barrier(0);
    float acc = 0.f;
#pragma unroll
    for (int tap = 0; tap < 27; ++tap) {
        const bool ok = (okm >> tap) & 1;
        const int   id = (ok && g[tap] >= 0) ? g[tap] : 0;
        const float m  = (ok && g[tap] >= 0) ? 1.f : 0.f;
        const float4 v = *(const float4*)(fin + (size_t)id * 4);
        const float* wp = w + (size_t)tap * 64 + c;
        float t = v.x*wp[0] + v.y*wp[16] + v.z*wp[32] + v.w*wp[48];
        acc = fmaf(m, t, acc);
    }
    out[(size_t)p*16 + c] = acc;
}

// Wave = 16 points x 16 couts; blockIdx.y = cout tile.
template<int CIN, int COUT, int KD, int KH, int KW>
__global__ __launch_bounds__(256, 4) void sp_conv_mfma(
    const unsigned short* __restrict__ fin, const int* __restrict__ grid,
    const int* __restrict__ oc, int n_out,
    const unsigned short* __restrict__ wt, float* __restrict__ out,
    float* __restrict__ stats,
    int D, int H, int W, int sz, int sy, int sx, int pz, int py, int px)
{
    constexpr int T = KD*KH*KW;
    __shared__ float ls[32];
    const int lane  = threadIdx.x & 63;
    const int wid   = threadIdx.x >> 6;
    const int n     = lane & 15;
    const int quad  = lane >> 4;
    const int cbase = blockIdx.y * 16;
    const int pbase = blockIdx.x * 64 + wid * 16;

    if (threadIdx.x < 32) ls[threadIdx.x] = 0.f;

    int pc = pbase + n;
    if (pc > n_out - 1) pc = n_out - 1;
    const int4 cc = ((const int4*)oc)[pc];
    const int* gb = grid + cc.x * (D * H * W);
    const int iz0 = cc.y * sz - pz;
    const int iy0 = cc.z * sy - py;
    const int ix0 = cc.w * sx - px;

    f32x4 acc = (f32x4){0.f, 0.f, 0.f, 0.f};

    if constexpr (CIN >= 32) {
        constexpr int S = CIN/32;
        constexpr int BATCH = (CIN >= 64) ? 4 : 7;
        constexpr int TP = ((T + BATCH - 1)/BATCH)*BATCH;   // 28 (T=27), 4 (T=3)
        // --- one pinned round of grid lookups
        int gval[TP];
        unsigned okm = 0;
#pragma unroll
        for (int tap = 0; tap < TP; ++tap) {
            const int te = tap < T ? tap : 0;
            const int kd = te/(KH*KW), kr = te%(KH*KW), kh = kr/KW, kw = kr%KW;
            const int iz = iz0 + kd, iy = iy0 + kh, ix = ix0 + kw;
            const bool ok = (tap < T) && (unsigned)iz < (unsigned)D &&
                            (unsigned)iy < (unsigned)H && (unsigned)ix < (unsigned)W;
            okm |= (unsigned)ok << tap;
            const int cz = iz < 0 ? 0 : (iz >= D ? D-1 : iz);
            const int cy = iy < 0 ? 0 : (iy >= H ? H-1 : iy);
            const int cx = ix < 0 ? 0 : (ix >= W ? W-1 : ix);
            gval[tap] = gb[(cz*H + cy)*W + cx];
        }
        __builtin_amdgcn_sched_barrier(0);
        int idx[TP];
#pragma unroll
        for (int tap = 0; tap < TP; ++tap)
            idx[tap] = ((okm >> tap) & 1) ? gval[tap] : -1;   // -1 -> zero pad row

#pragma unroll
        for (int t0 = 0; t0 < TP; t0 += BATCH) {
            bf16x8 a[BATCH][S], b[BATCH][S];
#pragma unroll
            for (int j = 0; j < BATCH; ++j)
#pragma unroll
                for (int s = 0; s < S; ++s)
                    a[j][s] = *(const bf16x8*)(fin + (ptrdiff_t)idx[t0+j]*CIN + s*32 + quad*8);
#pragma unroll
            for (int j = 0; j < BATCH; ++j) {
                const int tw = (t0+j) < T ? (t0+j) : T;     // pad slot zeroed
#pragma unroll
                for (int s = 0; s < S; ++s)
                    b[j][s] = *(const bf16x8*)(wt + ((size_t)tw*COUT + cbase + n)*CIN + s*32 + quad*8);
            }
            __builtin_amdgcn_sched_barrier(0);   // pin: whole batch in flight
#pragma unroll
            for (int j = 0; j < BATCH; ++j)
#pragma unroll
                for (int s = 0; s < S; ++s)
                    acc = __builtin_amdgcn_mfma_f32_16x16x32_bf16(a[j][s], b[j][s], acc, 0, 0, 0);
        }
    } else {  // CIN == 16: 2 taps per K=32 (quad>>1 picks tap); KB=14
        constexpr int KB = (T + 1) / 2;
        constexpr int BATCH = 7;
        const int cinb = (quad & 1) * 8;
        int gval[KB];
        unsigned okm = 0;
#pragma unroll
        for (int kb = 0; kb < KB; ++kb) {
            const int tap = 2*kb + (quad >> 1);
            const int te = tap < T ? tap : 0;
            const int kd = te/(KH*KW), kr = te%(KH*KW), kh = kr/KW, kw = kr%KW;
            const int iz = iz0 + kd, iy = iy0 + kh, ix = ix0 + kw;
            const bool ok = (tap < T) && (unsigned)iz < (unsigned)D &&
                            (unsigned)iy < (unsigned)H && (unsigned)ix < (unsigned)W;
            okm |= (unsigned)ok << kb;
            const int cz = iz < 0 ? 0 : (iz >= D ? D-1 : iz);
            const int cy = iy < 0 ? 0 : (iy >= H ? H-1 : iy);
            const int cx = ix < 0 ? 0 : (ix >= W ? W-1 : ix);
            gval[kb] = gb[(cz*H + cy)*W + cx];
        }
        __builtin_amdgcn_sched_barrier(0);
        int idx[KB];
#pragma unroll
        for (int kb = 0; kb < KB; ++kb)
            idx[kb] = ((okm >> kb) & 1) ? gval[kb] : -1;

#pragma unroll
        for (int k0 = 0; k0 < KB; k0 += BATCH) {
            bf16x8 a[BATCH], b[BATCH];
#pragma unroll
            for (int j = 0; j < BATCH; ++j)
                a[j] = *(const bf16x8*)(fin + (ptrdiff_t)idx[k0+j]*16 + cinb);
#pragma unroll
            for (int j = 0; j < BATCH; ++j) {
                const int tap = 2*(k0+j) + (quad >> 1);
                const int tw = tap < T ? tap : T;
                b[j] = *(const bf16x8*)(wt + ((size_t)tw*COUT + cbase + n)*16 + cinb);
            }
            __builtin_amdgcn_sched_barrier(0);
#pragma unroll
            for (int j = 0; j < BATCH; ++j)
                acc = __builtin_amdgcn_mfma_f32_16x16x32_bf16(a[j], b[j], acc, 0, 0, 0);
        }
    }

    // --- store raw fp32 (this block's 16-cout slice)
#pragma unroll
    for (int r = 0; r < 4; ++r) {
        const int p = pbase + quad*4 + r;
        if (p < n_out) out[(size_t)p * COUT + cbase + n] = acc[r];
    }

    // --- fused BN stats
    __syncthreads();
    {
        float s1 = 0.f, s2 = 0.f;
#pragma unroll
        for (int r = 0; r < 4; ++r) {
            const int p = pbase + quad*4 + r;
            if (p < n_out) { const float v = acc[r]; s1 += v; s2 += v*v; }
        }
        s1 += __shfl_xor(s1, 16); s2 += __shfl_xor(s2, 16);
        s1 += __shfl_xor(s1, 32); s2 += __shfl_xor(s2, 32);
        if (quad == 0) {
            atomicAdd(&ls[n], s1);
            atomicAdd(&ls[16 + n], s2);
        }
    }
    __syncthreads();
    if (threadIdx.x < 16)
        atomicAdd(&stats[cbase + threadIdx.x], ls[threadIdx.x]);
    else if (threadIdx.x < 32)
        atomicAdd(&stats[COUT + cbase + (threadIdx.x - 16)], ls[threadIdx.x]);
}

template<int C>
__global__ __launch_bounds__(256) void reduce_stats(const float* __restrict__ x, int nn,
                                                    float* __restrict__ stats)
{
    constexpr int R = 256 / C;
    __shared__ float s1[256];
    __shared__ float s2[256];
    const int c = threadIdx.x % C;
    const int r = threadIdx.x / C;
    float a1 = 0.f, a2 = 0.f;
    for (int i = blockIdx.x * R + r; i < nn; i += R * gridDim.x) {
        float v = x[(size_t)i*C + c];
        a1 += v;
        a2 += v * v;
    }
    s1[threadIdx.x] = a1;
    s2[threadIdx.x] = a2;
    __syncthreads();
    for (int off = 128; off >= C; off >>= 1) {
        if (threadIdx.x < off) {
            s1[threadIdx.x] += s1[threadIdx.x + off];
            s2[threadIdx.x] += s2[threadIdx.x + off];
        }
        __syncthreads();
    }
    if (threadIdx.x < C) {
        atomicAdd(&stats[c],     s1[threadIdx.x]);
        atomicAdd(&stats[C + c], s2[threadIdx.x]);
    }
}

__device__ inline void stv4(float* p, float4 v) { *(float4*)p = v; }
__device__ inline void stv4(unsigned short* p, float4 v) {
    bf16x4s o;
    o.x = (short)f2bf(v.x); o.y = (short)f2bf(v.y);
    o.z = (short)f2bf(v.z); o.w = (short)f2bf(v.w);
    *(bf16x4s*)p = o;
}

// 4 channels per thread, vectorized
template<int C, typename OUT>
__global__ __launch_bounds__(256) void bn_relu_apply(const float* __restrict__ x,
                                                     OUT* __restrict__ y, int nn,
                                                     const float* __restrict__ stats,
                                                     const float* __restrict__ gamma,
                                                     const float* __restrict__ beta)
{
    const size_t q = (size_t)blockIdx.x * blockDim.x + threadIdx.x;
    if (q >= (size_t)nn * (C/4)) return;
    const int c = (int)(q % (size_t)(C/4)) * 4;
    const float inv_n = 1.f / (float)nn;
    const float4 xv = *(const float4*)(x + q*4);
    const float4 s1 = *(const float4*)(stats + c);
    const float4 s2 = *(const float4*)(stats + C + c);
    const float4 gm = *(const float4*)(gamma + c);
    const float4 bt = *(const float4*)(beta + c);
    float4 o;
    {
        float mu = s1.x*inv_n, var = s2.x*inv_n - mu*mu, g = gm.x*rsqrtf(var+1e-3f);
        float v = (xv.x - mu)*g + bt.x; o.x = v > 0.f ? v : 0.f;
    }
    {
        float mu = s1.y*inv_n, var = s2.y*inv_n - mu*mu, g = gm.y*rsqrtf(var+1e-3f);
        float v = (xv.y - mu)*g + bt.y; o.y = v > 0.f ? v : 0.f;
    }
    {
        float mu = s1.z*inv_n, var = s2.z*inv_n - mu*mu, g = gm.z*rsqrtf(var+1e-3f);
        float v = (xv.z - mu)*g + bt.z; o.z = v > 0.f ? v : 0.f;
    }
    {
        float mu = s1.w*inv_n, var = s2.w*inv_n - mu*mu, g = gm.w*rsqrtf(var+1e-3f);
        float v = (xv.w - mu)*g + bt.w; o.w = v > 0.f ? v : 0.f;
    }
    stv4(y + q*4, o);
}

extern "C" void kernel_launch(void* const* d_in, const int* in_sizes, int n_in,
                              void* d_out, int out_size, void* d_ws, size_t ws_size,
                              hipStream_t stream) {
    const float* WPTR[12] = {
        (const float*)d_in[1], (const float*)d_in[2], (const float*)d_in[3],
        (const float*)d_in[4], (const float*)d_in[5], (const float*)d_in[6],
        (const float*)d_in[7], (const float*)d_in[8], (const float*)d_in[9],
        (const float*)d_in[10], (const float*)d_in[11], (const float*)d_in[12] };
    const float* vf    = (const float*)d_in[0];
    const float* gamma = (const float*)d_in[13];
    const float* beta  = (const float*)d_in[14];
    const int* c1 = (const int*)d_in[15];
    const int* c2 = (const int*)d_in[16];
    const int* c3 = (const int*)d_in[17];
    const int* c4 = (const int*)d_in[18];
    const int* c5 = (const int*)d_in[19];
    const int N1 = in_sizes[15] / 4;
    const int N2 = in_sizes[16] / 4;
    const int N3 = in_sizes[17] / 4;
    const int N4 = in_sizes[18] / 4;
    const int N5 = in_sizes[19] / 4;

    static const int LT[12]  = {27,27,27,27,27,27,27,27,27,27,27,3};
    static const int LCI[12] = {4,16,16,32,32,32,64,64,64,64,64,64};
    static const int LCO[12] = {16,16,32,32,32,64,64,64,64,64,64,128};

    const size_t G1 = (size_t)2*41*160*160;
    const size_t G2 = (size_t)2*21*80*80;
    const size_t G3 = (size_t)2*11*40*40;
    const size_t G4 = (size_t)2*5*20*20;
    int* grid1 = (int*)d_ws;
    int* grid2 = grid1 + G1;
    int* grid3 = grid2 + G2;
    int* grid4 = grid3 + G3;
    float* stats = (float*)(grid4 + G4);            // 12 x 256 floats

    size_t maxE = (size_t)N1*16;
    if ((size_t)N2*32  > maxE) maxE = (size_t)N2*32;
    if ((size_t)N3*64  > maxE) maxE = (size_t)N3*64;
    if ((size_t)N4*64  > maxE) maxE = (size_t)N4*64;
    if ((size_t)N5*128 > maxE) maxE = (size_t)N5*128;
    maxE = (maxE + 7) & ~(size_t)7;

    float* raw = stats + 12*256;                    // fp32 conv output
    unsigned short* padA = (unsigned short*)(raw + maxE);
    unsigned short* fA   = padA + 128;              // zero row lives at fA-CIN
    unsigned short* padB = fA + maxE;
    unsigned short* fB   = padB + 128;
    unsigned short* wtb  = fB + maxE;               // bf16 transposed weights
    size_t wtoff[12];
    {
        size_t o = 0;
        for (int i = 1; i < 12; ++i) {
            wtoff[i] = o;
            o += (size_t)(LT[i] + 1) * LCI[i] * LCO[i];
        }
    }

    hipMemsetAsync(grid1, 0xFF, (G1+G2+G3+G4)*sizeof(int), stream);
    hipMemsetAsync(stats, 0, 12*256*sizeof(float), stream);
    hipMemsetAsync(padA, 0, 128*sizeof(unsigned short), stream);
    hipMemsetAsync(padB, 0, 128*sizeof(unsigned short), stream);

    {
        ScatterArgs sa;
        sa.coords[0]=c1; sa.coords[1]=c2; sa.coords[2]=c3; sa.coords[3]=c4;
        sa.grid[0]=grid1; sa.grid[1]=grid2; sa.grid[2]=grid3; sa.grid[3]=grid4;
        sa.n[0]=N1; sa.n[1]=N2; sa.n[2]=N3; sa.n[3]=N4;
        sa.D[0]=41; sa.H[0]=160; sa.W[0]=160;
        sa.D[1]=21; sa.H[1]= 80; sa.W[1]= 80;
        sa.D[2]=11; sa.H[2]= 40; sa.W[2]= 40;
        sa.D[3]= 5; sa.H[3]= 20; sa.W[3]= 20;
        int mx = N1; if (N2>mx) mx=N2; if (N3>mx) mx=N3; if (N4>mx) mx=N4;
        dim3 g((mx + 255)/256, 4);
        scatter_grid_all<<<g, 256, 0, stream>>>(sa);
    }
    {
        PrepArgs pa;
        int mx = 0;
        for (int i = 1; i < 12; ++i) {
            pa.src[i-1] = WPTR[i];
            pa.dst[i-1] = wtb + wtoff[i];
            pa.T[i-1] = LT[i]; pa.CIN[i-1] = LCI[i]; pa.COUT[i-1] = LCO[i];
            pa.total[i-1] = (LT[i]+1)*LCI[i]*LCO[i];
            if (pa.total[i-1] > mx) mx = pa.total[i-1];
        }
        dim3 g((mx + 255)/256, 11);
        prep_w_all<<<g, 256, 0, stream>>>(pa);
    }

    enum { GOFF_0 = 0, GOFF_1 = 16, GOFF_2 = 32, GOFF_3 = 64, GOFF_4 = 96, GOFF_5 = 128,
           GOFF_6 = 192, GOFF_7 = 256, GOFF_8 = 320, GOFF_9 = 384, GOFF_10 = 448, GOFF_11 = 512 };

#define APPLY(i, COUT, NP, FOUT_T, FOUT) \
    bn_relu_apply<COUT, FOUT_T><<<(((size_t)(NP)*(COUT)/4) + 255)/256, 256, 0, stream>>>( \
        raw, FOUT, NP, stats + (i)*256, gamma + GOFF_##i, beta + GOFF_##i);

    // L0: fp32 VALU conv + separate stats reduce
    sp_conv0<<<((size_t)N1*16 + 255)/256, 256, 0, stream>>>(vf, grid1, c1, N1, WPTR[0], raw, 41,160,160);
    { int rb = (N1 + 15)/16; if (rb > 240) rb = 240;
      reduce_stats<16><<<rb, 256, 0, stream>>>(raw, N1, stats + 0*256); }
    APPLY(0, 16, N1, unsigned short, fA);

#define CONV(i, CIN, COUT, KD,KH,KW, FIN, GRD, OC, NP, D,H,W, SZ,SY,SX, PZ,PY,PX) \
    { dim3 g_(((NP)+63)/64, (COUT)/16); \
      sp_conv_mfma<CIN,COUT,KD,KH,KW><<<g_, 256, 0, stream>>>( \
          FIN, GRD, OC, NP, wtb + wtoff[i], raw, stats + (i)*256, D,H,W, SZ,SY,SX, PZ,PY,PX); }

    CONV( 1, 16, 16, 3,3,3, fA, grid1, c1, N1, 41,160,160, 1,1,1, 1,1,1); APPLY( 1, 16, N1, unsigned short, fB);
    CONV( 2, 16, 32, 3,3,3, fB, grid1, c2, N2, 41,160,160, 2,2,2, 1,1,1); APPLY( 2, 32, N2, unsigned short, fA);
    CONV( 3, 32, 32, 3,3,3, fA, grid2, c2, N2, 21, 80, 80, 1,1,1, 1,1,1); APPLY( 3, 32, N2, unsigned short, fB);
    CONV( 4, 32, 32, 3,3,3, fB, grid2, c2, N2, 21, 80, 80, 1,1,1, 1,1,1); APPLY( 4, 32, N2, unsigned short, fA);
    CONV( 5, 32, 64, 3,3,3, fA, grid2, c3, N3, 21, 80, 80, 2,2,2, 1,1,1); APPLY( 5, 64, N3, unsigned short, fB);
    CONV( 6, 64, 64, 3,3,3, fB, grid3, c3, N3, 11, 40, 40, 1,1,1, 1,1,1); APPLY( 6, 64, N3, unsigned short, fA);
    CONV( 7, 64, 64, 3,3,3, fA, grid3, c3, N3, 11, 40, 40, 1,1,1, 1,1,1); APPLY( 7, 64, N3, unsigned short, fB);
    CONV( 8, 64, 64, 3,3,3, fB, grid3, c4, N4, 11, 40, 40, 2,2,2, 0,1,1); APPLY( 8, 64, N4, unsigned short, fA);
    CONV( 9, 64, 64, 3,3,3, fA, grid4, c4, N4,  5, 20, 20, 1,1,1, 1,1,1); APPLY( 9, 64, N4, unsigned short, fB);
    CONV(10, 64, 64, 3,3,3, fB, grid4, c4, N4,  5, 20, 20, 1,1,1, 1,1,1); APPLY(10, 64, N4, unsigned short, fA);
    CONV(11, 64,128, 3,1,1, fA, grid4, c5, N5,  5, 20, 20, 2,1,1, 0,0,0); APPLY(11, 128, N5, float, (float*)d_out);
#undef CONV
#undef APPLY
}

// Round 9
// 419.597 us; speedup vs baseline: 1.5333x; 1.4476x over previous
//
#include <hip/hip_runtime.h>
#include <hip/hip_bf16.h>

// ---------------------------------------------------------------------------
// VoxelBackBone8x, R9: transaction-minimal MFMA sparse conv via LDS staging.
// R6-R8 invariance (116us at occ 28/48/34%) => per-CU TA transaction
// throughput is the wall (~4cyc x 72k transactions/CU matches 278k cyc).
// R9 cuts line-touches ~9x: A gathered as FULL 128B rows (8 lanes/row,
// XOR-swizzled chunks) via global_load_lds DMA (no dest VGPRs); B staged
// block-shared in LDS (4 waves cooperate, all reuse); wave covers all COUT
// so nothing is fetched per-cout-tile. Batched taps between barrier pairs.
// Verified MFMA layouts (learn_hip m89/m91):
//   A[m=lane&15][k=quad*8+j], B[n=lane&15][k=quad*8+j],
//   C/D col=lane&15, row=quad*4+reg.
// ---------------------------------------------------------------------------

typedef __attribute__((ext_vector_type(8))) short bf16x8;
typedef __attribute__((ext_vector_type(4))) short bf16x4s;
typedef __attribute__((ext_vector_type(4))) float f32x4;

typedef const __attribute__((address_space(1))) unsigned int* gas_ptr;
typedef __attribute__((address_space(3))) unsigned int* las_ptr;

__device__ __forceinline__ void dma16(const unsigned short* g, unsigned short* l) {
    __builtin_amdgcn_global_load_lds((gas_ptr)g, (las_ptr)l, 16, 0, 0);
}

__device__ inline unsigned short f2bf(float f) {
    unsigned u = __builtin_bit_cast(unsigned, f);
    u += 0x7FFFu + ((u >> 16) & 1u);
    return (unsigned short)(u >> 16);
}

struct ScatterArgs {
    const int* coords[4];
    int* grid[4];
    int n[4];
    int D[4], H[4], W[4];
};

__global__ __launch_bounds__(256) void scatter_grid_all(ScatterArgs a) {
    const int l = blockIdx.y;
    const int i = blockIdx.x * 256 + threadIdx.x;
    if (i >= a.n[l]) return;
    const int* c = a.coords[l] + 4 * i;
    a.grid[l][((c[0] * a.D[l] + c[1]) * a.H[l] + c[2]) * a.W[l] + c[3]] = i;
}

struct PrepArgs {
    const float* src[11];
    unsigned short* dst[11];
    int T[11], CIN[11], COUT[11], total[11];
};

// fp32 [t][cin][cout] -> bf16 [t][cout][cin]; pad tap T zeroed
__global__ __launch_bounds__(256) void prep_w_all(PrepArgs a) {
    const int l = blockIdx.y;
    const int i = blockIdx.x * 256 + threadIdx.x;
    if (i >= a.total[l]) return;
    const int COUT = a.COUT[l], CIN = a.CIN[l], T = a.T[l];
    const int co = i % COUT; const int r = i / COUT; const int ci = r % CIN; const int t = r / CIN;
    unsigned short v = (t < T) ? f2bf(a.src[l][i]) : (unsigned short)0;
    a.dst[l][((size_t)t * COUT + co) * CIN + ci] = v;
}

// Layer 0: CIN=4 -> COUT=16
__global__ __launch_bounds__(256, 4) void sp_conv0(const float* __restrict__ fin,
                                                   const int* __restrict__ grid,
                                                   const int* __restrict__ oc, int n_out,
                                                   const float* __restrict__ w,
                                                   float* __restrict__ out,
                                                   int D, int H, int W) {
    const int c = threadIdx.x & 15;
    const int p = (blockIdx.x * 256 + threadIdx.x) >> 4;
    if (p >= n_out) return;
    const int b   = oc[4*p+0];
    const int iz0 = oc[4*p+1] - 1;
    const int iy0 = oc[4*p+2] - 1;
    const int ix0 = oc[4*p+3] - 1;
    const int* gb = grid + b * (D * H * W);
    float acc = 0.f;
    for (int kd = 0; kd < 3; ++kd) {
        const int iz = iz0 + kd;
        if ((unsigned)iz >= (unsigned)D) continue;
        for (int kh = 0; kh < 3; ++kh) {
            const int iy = iy0 + kh;
            if ((unsigned)iy >= (unsigned)H) continue;
            for (int kw = 0; kw < 3; ++kw) {
                const int ix = ix0 + kw;
                if ((unsigned)ix >= (unsigned)W) continue;
                const int idx = gb[(iz*H + iy)*W + ix];
                if (idx < 0) continue;
                const float4 v = *(const float4*)(fin + (size_t)idx * 4);
                const float* wp = w + (size_t)((kd*3 + kh)*3 + kw) * 64 + c;
                acc = fmaf(v.x, wp[0],  acc);
                acc = fmaf(v.y, wp[16], acc);
                acc = fmaf(v.z, wp[32], acc);
                acc = fmaf(v.w, wp[48], acc);
            }
        }
    }
    out[(size_t)p*16 + c] = acc;
}

// ---------------------------------------------------------------------------
// CIN=16 register path (layers 1,2). Wave = 16pts x 16couts, blockIdx.y=ctile.
// ---------------------------------------------------------------------------
template<int COUT>
__global__ __launch_bounds__(256, 4) void sp_conv16(
    const unsigned short* __restrict__ fin, const int* __restrict__ grid,
    const int* __restrict__ oc, int n_out,
    const unsigned short* __restrict__ wt, float* __restrict__ out,
    float* __restrict__ stats,
    int D, int H, int W, int sz, int sy, int sx, int pz, int py, int px)
{
    constexpr int T = 27;
    constexpr int KB = 14;
    __shared__ float ls[32];
    const int lane  = threadIdx.x & 63;
    const int wid   = threadIdx.x >> 6;
    const int n     = lane & 15;
    const int quad  = lane >> 4;
    const int cbase = blockIdx.y * 16;
    const int pbase = blockIdx.x * 64 + wid * 16;

    if (threadIdx.x < 32) ls[threadIdx.x] = 0.f;

    int pc = pbase + n;
    if (pc > n_out - 1) pc = n_out - 1;
    const int4 cc = ((const int4*)oc)[pc];
    const int* gb = grid + cc.x * (D * H * W);
    const int iz0 = cc.y * sz - pz;
    const int iy0 = cc.z * sy - py;
    const int ix0 = cc.w * sx - px;

    f32x4 acc = (f32x4){0.f, 0.f, 0.f, 0.f};
    const int cinb = (quad & 1) * 8;
    int idx[KB];
#pragma unroll
    for (int kb = 0; kb < KB; ++kb) {
        const int tap = 2*kb + (quad >> 1);
        const int te = tap < T ? tap : 0;
        const int kd = te/9, kr = te%9, kh = kr/3, kw = kr%3;
        const int iz = iz0 + kd, iy = iy0 + kh, ix = ix0 + kw;
        const bool ok = (tap < T) && (unsigned)iz < (unsigned)D &&
                        (unsigned)iy < (unsigned)H && (unsigned)ix < (unsigned)W;
        const int cz = iz < 0 ? 0 : (iz >= D ? D-1 : iz);
        const int cy = iy < 0 ? 0 : (iy >= H ? H-1 : iy);
        const int cx = ix < 0 ? 0 : (ix >= W ? W-1 : ix);
        const int g = gb[(cz*H + cy)*W + cx];
        idx[kb] = ok ? g : -1;
    }
#pragma unroll
    for (int k0 = 0; k0 < KB; k0 += 7) {
        bf16x8 a[7], b[7];
#pragma unroll
        for (int j = 0; j < 7; ++j)
            a[j] = *(const bf16x8*)(fin + (ptrdiff_t)idx[k0+j]*16 + cinb);
#pragma unroll
        for (int j = 0; j < 7; ++j) {
            const int tap = 2*(k0+j) + (quad >> 1);
            const int tw = tap < T ? tap : T;
            b[j] = *(const bf16x8*)(wt + ((size_t)tw*COUT + cbase + n)*16 + cinb);
        }
        __builtin_amdgcn_sched_barrier(0);
#pragma unroll
        for (int j = 0; j < 7; ++j)
            acc = __builtin_amdgcn_mfma_f32_16x16x32_bf16(a[j], b[j], acc, 0, 0, 0);
    }

#pragma unroll
    for (int r = 0; r < 4; ++r) {
        const int p = pbase + quad*4 + r;
        if (p < n_out) out[(size_t)p * COUT + cbase + n] = acc[r];
    }
    __syncthreads();
    {
        float s1 = 0.f, s2 = 0.f;
#pragma unroll
        for (int r = 0; r < 4; ++r) {
            const int p = pbase + quad*4 + r;
            if (p < n_out) { const float v = acc[r]; s1 += v; s2 += v*v; }
        }
        s1 += __shfl_xor(s1, 16); s2 += __shfl_xor(s2, 16);
        s1 += __shfl_xor(s1, 32); s2 += __shfl_xor(s2, 32);
        if (quad == 0) { atomicAdd(&ls[n], s1); atomicAdd(&ls[16+n], s2); }
    }
    __syncthreads();
    if (threadIdx.x < 16)
        atomicAdd(&stats[cbase + threadIdx.x], ls[threadIdx.x]);
    else if (threadIdx.x < 32)
        atomicAdd(&stats[COUT + cbase + (threadIdx.x - 16)], ls[threadIdx.x]);
}

// ---------------------------------------------------------------------------
// LDS-staged path (CIN>=32). Block = 64 pts (4 waves x 16), wave computes all
// COUT. A: wave-private LDS, full-row coalesced DMA. B: block-shared LDS.
// XOR chunk swizzle makes ds_read_b128 2-way (free) on banks.
// ---------------------------------------------------------------------------
template<int CIN, int COUT, int BT, int KD, int KH, int KW>
__global__ __launch_bounds__(256, 2) void sp_conv_lds(
    const unsigned short* __restrict__ fin, const int* __restrict__ grid,
    const int* __restrict__ oc, int n_out,
    const unsigned short* __restrict__ wt, float* __restrict__ out,
    float* __restrict__ stats,
    int D, int H, int W, int sz, int sy, int sx, int pz, int py, int px)
{
    constexpr int T    = KD*KH*KW;
    constexpr int TP   = ((T + BT - 1)/BT)*BT;
    constexpr int NT   = COUT/16;
    constexpr int S    = CIN/32;
    constexpr int LPR  = CIN/8;          // lanes per row (chunks of 16B)
    constexpr int RPD  = 64/LPR;         // rows per DMA
    constexpr int ADMA = 16/RPD;         // A DMAs per tap (wave-private)
    constexpr int BDMA = COUT/RPD;       // B DMAs per tap (block total)

    __shared__ unsigned short Abuf[4*BT*16*CIN];
    __shared__ unsigned short Bbuf[BT*COUT*CIN];
    __shared__ float ls[2*COUT];

    const int l     = threadIdx.x & 63;
    const int w     = threadIdx.x >> 6;
    const int n     = l & 15;
    const int quad  = l >> 4;
    const int pbase = blockIdx.x * 64 + w * 16;

    if (threadIdx.x < 2*COUT) ls[threadIdx.x] = 0.f;

    int pc = pbase + n;
    if (pc > n_out - 1) pc = n_out - 1;
    const int4 cc = ((const int4*)oc)[pc];
    const int* gb = grid + cc.x * (D * H * W);
    const int iz0 = cc.y * sz - pz;
    const int iy0 = cc.z * sy - py;
    const int ix0 = cc.w * sx - px;

    // --- tap indices for point n (branchless clamped lookups)
    int idx[TP];
#pragma unroll
    for (int tap = 0; tap < TP; ++tap) {
        const int te = tap < T ? tap : 0;
        const int kd = te/(KH*KW), kr = te%(KH*KW), kh = kr/KW, kw = kr%KW;
        const int iz = iz0 + kd, iy = iy0 + kh, ix = ix0 + kw;
        const bool ok = (tap < T) && (unsigned)iz < (unsigned)D &&
                        (unsigned)iy < (unsigned)H && (unsigned)ix < (unsigned)W;
        const int cz = iz < 0 ? 0 : (iz >= D ? D-1 : iz);
        const int cy = iy < 0 ? 0 : (iy >= H ? H-1 : iy);
        const int cx = ix < 0 ? 0 : (ix >= W ? W-1 : ix);
        const int g = gb[(cz*H + cy)*W + cx];
        idx[tap] = ok ? g : -1;          // -1 -> zero pad row before fin
    }

    f32x4 acc[NT];
#pragma unroll
    for (int t = 0; t < NT; ++t) acc[t] = (f32x4){0.f, 0.f, 0.f, 0.f};

#pragma unroll
    for (int tb0 = 0; tb0 < TP; tb0 += BT) {
        // --- A DMAs: full-row coalesced; lane's source row via shfl of idx
#pragma unroll
        for (int j = 0; j < BT; ++j) {
#pragma unroll
            for (int d = 0; d < ADMA; ++d) {
                const int m  = d*RPD + l/LPR;
                const int i0 = __shfl(idx[tb0+j], m, 16);
                const int slot = (l % LPR) ^ (m % LPR);
                const unsigned short* gp = fin + (ptrdiff_t)i0*CIN + slot*8;
                unsigned short* lp = Abuf + ((w*BT + j)*16 + d*RPD)*CIN;
                dma16(gp, lp);
            }
        }
        // --- B DMAs: block-shared, wave takes every 4th
        for (int q = w; q < BT*BDMA; q += 4) {
            const int j = q / BDMA, d = q % BDMA;
            const int t = tb0 + j;
            const int tw = t < T ? t : T;          // pad slot zeroed by prep
            const int r  = d*RPD + l/LPR;
            const int slot = (l % LPR) ^ (r % LPR);
            const unsigned short* gp = wt + ((size_t)tw*COUT + r)*CIN + slot*8;
            unsigned short* lp = Bbuf + (j*COUT + d*RPD)*CIN;
            dma16(gp, lp);
        }
        __syncthreads();
        // --- compute
#pragma unroll
        for (int j = 0; j < BT; ++j) {
            const unsigned short* Aw = Abuf + (w*BT + j)*16*CIN;
            const unsigned short* Bw = Bbuf + j*COUT*CIN;
#pragma unroll
            for (int s = 0; s < S; ++s) {
                const int c = s*4 + quad;
                bf16x8 a = *(const bf16x8*)(Aw + n*CIN + ((c ^ (n % LPR)) * 8));
#pragma unroll
                for (int t = 0; t < NT; ++t) {
                    const int r = t*16 + n;
                    bf16x8 b = *(const bf16x8*)(Bw + r*CIN + ((c ^ (r % LPR)) * 8));
                    acc[t] = __builtin_amdgcn_mfma_f32_16x16x32_bf16(a, b, acc[t], 0, 0, 0);
                }
            }
        }
        __syncthreads();
    }

    // --- store raw fp32
#pragma unroll
    for (int t = 0; t < NT; ++t)
#pragma unroll
        for (int r = 0; r < 4; ++r) {
            const int p = pbase + quad*4 + r;
            if (p < n_out) out[(size_t)p * COUT + t*16 + n] = acc[t][r];
        }

    // --- fused BN stats
#pragma unroll
    for (int t = 0; t < NT; ++t) {
        float s1 = 0.f, s2 = 0.f;
#pragma unroll
        for (int r = 0; r < 4; ++r) {
            const int p = pbase + quad*4 + r;
            if (p < n_out) { const float v = acc[t][r]; s1 += v; s2 += v*v; }
        }
        s1 += __shfl_xor(s1, 16); s2 += __shfl_xor(s2, 16);
        s1 += __shfl_xor(s1, 32); s2 += __shfl_xor(s2, 32);
        if (quad == 0) {
            atomicAdd(&ls[t*16 + n], s1);
            atomicAdd(&ls[COUT + t*16 + n], s2);
        }
    }
    __syncthreads();
    if (threadIdx.x < 2*COUT) atomicAdd(&stats[threadIdx.x], ls[threadIdx.x]);
}

template<int C>
__global__ __launch_bounds__(256) void reduce_stats(const float* __restrict__ x, int nn,
                                                    float* __restrict__ stats)
{
    constexpr int R = 256 / C;
    __shared__ float s1[256];
    __shared__ float s2[256];
    const int c = threadIdx.x % C;
    const int r = threadIdx.x / C;
    float a1 = 0.f, a2 = 0.f;
    for (int i = blockIdx.x * R + r; i < nn; i += R * gridDim.x) {
        float v = x[(size_t)i*C + c];
        a1 += v;
        a2 += v * v;
    }
    s1[threadIdx.x] = a1;
    s2[threadIdx.x] = a2;
    __syncthreads();
    for (int off = 128; off >= C; off >>= 1) {
        if (threadIdx.x < off) {
            s1[threadIdx.x] += s1[threadIdx.x + off];
            s2[threadIdx.x] += s2[threadIdx.x + off];
        }
        __syncthreads();
    }
    if (threadIdx.x < C) {
        atomicAdd(&stats[c],     s1[threadIdx.x]);
        atomicAdd(&stats[C + c], s2[threadIdx.x]);
    }
}

__device__ inline void stv4(float* p, float4 v) { *(float4*)p = v; }
__device__ inline void stv4(unsigned short* p, float4 v) {
    bf16x4s o;
    o.x = (short)f2bf(v.x); o.y = (short)f2bf(v.y);
    o.z = (short)f2bf(v.z); o.w = (short)f2bf(v.w);
    *(bf16x4s*)p = o;
}

template<int C, typename OUT>
__global__ __launch_bounds__(256) void bn_relu_apply(const float* __restrict__ x,
                                                     OUT* __restrict__ y, int nn,
                                                     const float* __restrict__ stats,
                                                     const float* __restrict__ gamma,
                                                     const float* __restrict__ beta)
{
    const size_t q = (size_t)blockIdx.x * blockDim.x + threadIdx.x;
    if (q >= (size_t)nn * (C/4)) return;
    const int c = (int)(q % (size_t)(C/4)) * 4;
    const float inv_n = 1.f / (float)nn;
    const float4 xv = *(const float4*)(x + q*4);
    const float4 s1 = *(const float4*)(stats + c);
    const float4 s2 = *(const float4*)(stats + C + c);
    const float4 gm = *(const float4*)(gamma + c);
    const float4 bt = *(const float4*)(beta + c);
    float4 o;
    { float mu=s1.x*inv_n, var=s2.x*inv_n-mu*mu, g=gm.x*rsqrtf(var+1e-3f);
      float v=(xv.x-mu)*g+bt.x; o.x = v>0.f? v:0.f; }
    { float mu=s1.y*inv_n, var=s2.y*inv_n-mu*mu, g=gm.y*rsqrtf(var+1e-3f);
      float v=(xv.y-mu)*g+bt.y; o.y = v>0.f? v:0.f; }
    { float mu=s1.z*inv_n, var=s2.z*inv_n-mu*mu, g=gm.z*rsqrtf(var+1e-3f);
      float v=(xv.z-mu)*g+bt.z; o.z = v>0.f? v:0.f; }
    { float mu=s1.w*inv_n, var=s2.w*inv_n-mu*mu, g=gm.w*rsqrtf(var+1e-3f);
      float v=(xv.w-mu)*g+bt.w; o.w = v>0.f? v:0.f; }
    stv4(y + q*4, o);
}

extern "C" void kernel_launch(void* const* d_in, const int* in_sizes, int n_in,
                              void* d_out, int out_size, void* d_ws, size_t ws_size,
                              hipStream_t stream) {
    const float* WPTR[12] = {
        (const float*)d_in[1], (const float*)d_in[2], (const float*)d_in[3],
        (const float*)d_in[4], (const float*)d_in[5], (const float*)d_in[6],
        (const float*)d_in[7], (const float*)d_in[8], (const float*)d_in[9],
        (const float*)d_in[10], (const float*)d_in[11], (const float*)d_in[12] };
    const float* vf    = (const float*)d_in[0];
    const float* gamma = (const float*)d_in[13];
    const float* beta  = (const float*)d_in[14];
    const int* c1 = (const int*)d_in[15];
    const int* c2 = (const int*)d_in[16];
    const int* c3 = (const int*)d_in[17];
    const int* c4 = (const int*)d_in[18];
    const int* c5 = (const int*)d_in[19];
    const int N1 = in_sizes[15] / 4;
    const int N2 = in_sizes[16] / 4;
    const int N3 = in_sizes[17] / 4;
    const int N4 = in_sizes[18] / 4;
    const int N5 = in_sizes[19] / 4;

    static const int LT[12]  = {27,27,27,27,27,27,27,27,27,27,27,3};
    static const int LCI[12] = {4,16,16,32,32,32,64,64,64,64,64,64};
    static const int LCO[12] = {16,16,32,32,32,64,64,64,64,64,64,128};

    const size_t G1 = (size_t)2*41*160*160;
    const size_t G2 = (size_t)2*21*80*80;
    const size_t G3 = (size_t)2*11*40*40;
    const size_t G4 = (size_t)2*5*20*20;
    int* grid1 = (int*)d_ws;
    int* grid2 = grid1 + G1;
    int* grid3 = grid2 + G2;
    int* grid4 = grid3 + G3;
    float* stats = (float*)(grid4 + G4);

    size_t maxE = (size_t)N1*16;
    if ((size_t)N2*32  > maxE) maxE = (size_t)N2*32;
    if ((size_t)N3*64  > maxE) maxE = (size_t)N3*64;
    if ((size_t)N4*64  > maxE) maxE = (size_t)N4*64;
    if ((size_t)N5*128 > maxE) maxE = (size_t)N5*128;
    maxE = (maxE + 7) & ~(size_t)7;

    float* raw = stats + 12*256;
    unsigned short* padA = (unsigned short*)(raw + maxE);
    unsigned short* fA   = padA + 128;              // zero row at fA - CIN
    unsigned short* padB = fA + maxE;
    unsigned short* fB   = padB + 128;
    unsigned short* wtb  = fB + maxE;
    size_t wtoff[12];
    {
        size_t o = 0;
        for (int i = 1; i < 12; ++i) {
            wtoff[i] = o;
            o += (size_t)(LT[i] + 1) * LCI[i] * LCO[i];
        }
    }

    hipMemsetAsync(grid1, 0xFF, (G1+G2+G3+G4)*sizeof(int), stream);
    hipMemsetAsync(stats, 0, 12*256*sizeof(float), stream);
    hipMemsetAsync(padA, 0, 128*sizeof(unsigned short), stream);
    hipMemsetAsync(padB, 0, 128*sizeof(unsigned short), stream);

    {
        ScatterArgs sa;
        sa.coords[0]=c1; sa.coords[1]=c2; sa.coords[2]=c3; sa.coords[3]=c4;
        sa.grid[0]=grid1; sa.grid[1]=grid2; sa.grid[2]=grid3; sa.grid[3]=grid4;
        sa.n[0]=N1; sa.n[1]=N2; sa.n[2]=N3; sa.n[3]=N4;
        sa.D[0]=41; sa.H[0]=160; sa.W[0]=160;
        sa.D[1]=21; sa.H[1]= 80; sa.W[1]= 80;
        sa.D[2]=11; sa.H[2]= 40; sa.W[2]= 40;
        sa.D[3]= 5; sa.H[3]= 20; sa.W[3]= 20;
        int mx = N1; if (N2>mx) mx=N2; if (N3>mx) mx=N3; if (N4>mx) mx=N4;
        dim3 g((mx + 255)/256, 4);
        scatter_grid_all<<<g, 256, 0, stream>>>(sa);
    }
    {
        PrepArgs pa;
        int mx = 0;
        for (int i = 1; i < 12; ++i) {
            pa.src[i-1] = WPTR[i];
            pa.dst[i-1] = wtb + wtoff[i];
            pa.T[i-1] = LT[i]; pa.CIN[i-1] = LCI[i]; pa.COUT[i-1] = LCO[i];
            pa.total[i-1] = (LT[i]+1)*LCI[i]*LCO[i];
            if (pa.total[i-1] > mx) mx = pa.total[i-1];
        }
        dim3 g((mx + 255)/256, 11);
        prep_w_all<<<g, 256, 0, stream>>>(pa);
    }

    enum { GOFF_0 = 0, GOFF_1 = 16, GOFF_2 = 32, GOFF_3 = 64, GOFF_4 = 96, GOFF_5 = 128,
           GOFF_6 = 192, GOFF_7 = 256, GOFF_8 = 320, GOFF_9 = 384, GOFF_10 = 448, GOFF_11 = 512 };

#define APPLY(i, COUT, NP, FOUT_T, FOUT) \
    bn_relu_apply<COUT, FOUT_T><<<(((size_t)(NP)*(COUT)/4) + 255)/256, 256, 0, stream>>>( \
        raw, FOUT, NP, stats + (i)*256, gamma + GOFF_##i, beta + GOFF_##i);

    sp_conv0<<<((size_t)N1*16 + 255)/256, 256, 0, stream>>>(vf, grid1, c1, N1, WPTR[0], raw, 41,160,160);
    { int rb = (N1 + 15)/16; if (rb > 240) rb = 240;
      reduce_stats<16><<<rb, 256, 0, stream>>>(raw, N1, stats + 0*256); }
    APPLY(0, 16, N1, unsigned short, fA);

#define CONV16(i, COUT, FIN, GRD, OC, NP, D,H,W, SZ,SY,SX, PZ,PY,PX) \
    { dim3 g_(((NP)+63)/64, (COUT)/16); \
      sp_conv16<COUT><<<g_, 256, 0, stream>>>( \
          FIN, GRD, OC, NP, wtb + wtoff[i], raw, stats + (i)*256, D,H,W, SZ,SY,SX, PZ,PY,PX); }

#define CONVL(i, CIN, COUT, BT, KD,KH,KW, FIN, GRD, OC, NP, D,H,W, SZ,SY,SX, PZ,PY,PX) \
    sp_conv_lds<CIN,COUT,BT,KD,KH,KW><<<((NP)+63)/64, 256, 0, stream>>>( \
        FIN, GRD, OC, NP, wtb + wtoff[i], raw, stats + (i)*256, D,H,W, SZ,SY,SX, PZ,PY,PX);

    CONV16( 1, 16,       fA, grid1, c1, N1, 41,160,160, 1,1,1, 1,1,1); APPLY( 1, 16, N1, unsigned short, fB);
    CONV16( 2, 32,       fB, grid1, c2, N2, 41,160,160, 2,2,2, 1,1,1); APPLY( 2, 32, N2, unsigned short, fA);
    CONVL ( 3, 32, 32, 7, 3,3,3, fA, grid2, c2, N2, 21, 80, 80, 1,1,1, 1,1,1); APPLY( 3, 32, N2, unsigned short, fB);
    CONVL ( 4, 32, 32, 7, 3,3,3, fB, grid2, c2, N2, 21, 80, 80, 1,1,1, 1,1,1); APPLY( 4, 32, N2, unsigned short, fA);
    CONVL ( 5, 32, 64, 7, 3,3,3, fA, grid2, c3, N3, 21, 80, 80, 2,2,2, 1,1,1); APPLY( 5, 64, N3, unsigned short, fB);
    CONVL ( 6, 64, 64, 3, 3,3,3, fB, grid3, c3, N3, 11, 40, 40, 1,1,1, 1,1,1); APPLY( 6, 64, N3, unsigned short, fA);
    CONVL ( 7, 64, 64, 3, 3,3,3, fA, grid3, c3, N3, 11, 40, 40, 1,1,1, 1,1,1); APPLY( 7, 64, N3, unsigned short, fB);
    CONVL ( 8, 64, 64, 3, 3,3,3, fB, grid3, c4, N4, 11, 40, 40, 2,2,2, 0,1,1); APPLY( 8, 64, N4, unsigned short, fA);
    CONVL ( 9, 64, 64, 3, 3,3,3, fA, grid4, c4, N4,  5, 20, 20, 1,1,1, 1,1,1); APPLY( 9, 64, N4, unsigned short, fB);
    CONVL (10, 64, 64, 3, 3,3,3, fB, grid4, c4, N4,  5, 20, 20, 1,1,1, 1,1,1); APPLY(10, 64, N4, unsigned short, fA);
    CONVL (11, 64,128, 1, 3,1,1, fA, grid4, c5, N5,  5, 20, 20, 2,1,1, 0,0,0); APPLY(11, 128, N5, float, (float*)d_out);
#undef CONV16
#undef CONVL
#undef APPLY
}

// Round 10
// 407.386 us; speedup vs baseline: 1.5793x; 1.0300x over previous
//
#include <hip/hip_runtime.h>
#include <hip/hip_bf16.h>

// ---------------------------------------------------------------------------
// VoxelBackBone8x, R10: all-LDS-DMA MFMA sparse conv.
// R9 (607->420us) validated transaction-minimization via global_load_lds
// full-row staging. R10: (1) CIN=16 layers (L1,L2) ported to the LDS path
// (one DMA instr = 2 taps x 16 rows x 32B; lane-linear dest IS the frag
// layout), (2) grid lookups computed on quad 0 only (4x fewer probe
// transactions), fanned out via width-64 shfl.
// Verified MFMA layouts (learn_hip m89/m91):
//   A[m=lane&15][k=quad*8+j], B[n=lane&15][k=quad*8+j],
//   C/D col=lane&15, row=quad*4+reg.
// ---------------------------------------------------------------------------

typedef __attribute__((ext_vector_type(8))) short bf16x8;
typedef __attribute__((ext_vector_type(4))) short bf16x4s;
typedef __attribute__((ext_vector_type(4))) float f32x4;

typedef const __attribute__((address_space(1))) unsigned int* gas_ptr;
typedef __attribute__((address_space(3))) unsigned int* las_ptr;

__device__ __forceinline__ void dma16(const unsigned short* g, unsigned short* l) {
    __builtin_amdgcn_global_load_lds((gas_ptr)g, (las_ptr)l, 16, 0, 0);
}

__device__ inline unsigned short f2bf(float f) {
    unsigned u = __builtin_bit_cast(unsigned, f);
    u += 0x7FFFu + ((u >> 16) & 1u);
    return (unsigned short)(u >> 16);
}

struct ScatterArgs {
    const int* coords[4];
    int* grid[4];
    int n[4];
    int D[4], H[4], W[4];
};

__global__ __launch_bounds__(256) void scatter_grid_all(ScatterArgs a) {
    const int l = blockIdx.y;
    const int i = blockIdx.x * 256 + threadIdx.x;
    if (i >= a.n[l]) return;
    const int* c = a.coords[l] + 4 * i;
    a.grid[l][((c[0] * a.D[l] + c[1]) * a.H[l] + c[2]) * a.W[l] + c[3]] = i;
}

struct PrepArgs {
    const float* src[11];
    unsigned short* dst[11];
    int T[11], CIN[11], COUT[11], total[11];
};

// fp32 [t][cin][cout] -> bf16 [t][cout][cin]; pad tap T zeroed
__global__ __launch_bounds__(256) void prep_w_all(PrepArgs a) {
    const int l = blockIdx.y;
    const int i = blockIdx.x * 256 + threadIdx.x;
    if (i >= a.total[l]) return;
    const int COUT = a.COUT[l], CIN = a.CIN[l], T = a.T[l];
    const int co = i % COUT; const int r = i / COUT; const int ci = r % CIN; const int t = r / CIN;
    unsigned short v = (t < T) ? f2bf(a.src[l][i]) : (unsigned short)0;
    a.dst[l][((size_t)t * COUT + co) * CIN + ci] = v;
}

// Layer 0: CIN=4 -> COUT=16
__global__ __launch_bounds__(256, 4) void sp_conv0(const float* __restrict__ fin,
                                                   const int* __restrict__ grid,
                                                   const int* __restrict__ oc, int n_out,
                                                   const float* __restrict__ w,
                                                   float* __restrict__ out,
                                                   int D, int H, int W) {
    const int c = threadIdx.x & 15;
    const int p = (blockIdx.x * 256 + threadIdx.x) >> 4;
    if (p >= n_out) return;
    const int b   = oc[4*p+0];
    const int iz0 = oc[4*p+1] - 1;
    const int iy0 = oc[4*p+2] - 1;
    const int ix0 = oc[4*p+3] - 1;
    const int* gb = grid + b * (D * H * W);
    float acc = 0.f;
    for (int kd = 0; kd < 3; ++kd) {
        const int iz = iz0 + kd;
        if ((unsigned)iz >= (unsigned)D) continue;
        for (int kh = 0; kh < 3; ++kh) {
            const int iy = iy0 + kh;
            if ((unsigned)iy >= (unsigned)H) continue;
            for (int kw = 0; kw < 3; ++kw) {
                const int ix = ix0 + kw;
                if ((unsigned)ix >= (unsigned)W) continue;
                const int idx = gb[(iz*H + iy)*W + ix];
                if (idx < 0) continue;
                const float4 v = *(const float4*)(fin + (size_t)idx * 4);
                const float* wp = w + (size_t)((kd*3 + kh)*3 + kw) * 64 + c;
                acc = fmaf(v.x, wp[0],  acc);
                acc = fmaf(v.y, wp[16], acc);
                acc = fmaf(v.z, wp[32], acc);
                acc = fmaf(v.w, wp[48], acc);
            }
        }
    }
    out[(size_t)p*16 + c] = acc;
}

// ---------------------------------------------------------------------------
// LDS path, CIN=16 (layers 1,2). Block = 64 pts (4 waves x 16pts), wave does
// all COUT. One A-DMA instr = 2 taps x 16 rows x 32B (lane = [h][m][chunk]).
// K=32 MFMA consumes a tap pair: tap = quad>>1, cin-half = quad&1.
// ---------------------------------------------------------------------------
template<int COUT>
__global__ __launch_bounds__(256, 4) void sp_conv_lds16(
    const unsigned short* __restrict__ fin, const int* __restrict__ grid,
    const int* __restrict__ oc, int n_out,
    const unsigned short* __restrict__ wt, float* __restrict__ out,
    float* __restrict__ stats,
    int D, int H, int W, int sz, int sy, int sx, int pz, int py, int px)
{
    constexpr int T  = 27;
    constexpr int BT = 4;                 // taps per batch (even)
    constexpr int TP = 28;
    constexpr int NT = COUT/16;
    constexpr int NB = (COUT == 16) ? BT/2 : BT;   // B-DMA instrs per batch

    __shared__ unsigned short Abuf[4*BT*16*16];
    __shared__ unsigned short Bbuf[BT*COUT*16];
    __shared__ float ls[2*COUT];

    const int l     = threadIdx.x & 63;
    const int w     = threadIdx.x >> 6;
    const int n     = l & 15;
    const int quad  = l >> 4;
    const int pbase = blockIdx.x * 64 + w * 16;

    if (threadIdx.x < 2*COUT) ls[threadIdx.x] = 0.f;

    // --- tap indices: computed on quad 0 only (4x fewer grid probes)
    int idx[TP];
    if (quad == 0) {
        int pc = pbase + n;
        if (pc > n_out - 1) pc = n_out - 1;
        const int4 cc = ((const int4*)oc)[pc];
        const int* gb = grid + cc.x * (D * H * W);
        const int iz0 = cc.y * sz - pz;
        const int iy0 = cc.z * sy - py;
        const int ix0 = cc.w * sx - px;
#pragma unroll
        for (int tap = 0; tap < TP; ++tap) {
            const int te = tap < T ? tap : 0;
            const int kd = te/9, kr = te%9, kh = kr/3, kw = kr%3;
            const int iz = iz0 + kd, iy = iy0 + kh, ix = ix0 + kw;
            const bool ok = (tap < T) && (unsigned)iz < (unsigned)D &&
                            (unsigned)iy < (unsigned)H && (unsigned)ix < (unsigned)W;
            const int cz = iz < 0 ? 0 : (iz >= D ? D-1 : iz);
            const int cy = iy < 0 ? 0 : (iy >= H ? H-1 : iy);
            const int cx = ix < 0 ? 0 : (ix >= W ? W-1 : ix);
            const int g = gb[(cz*H + cy)*W + cx];
            idx[tap] = ok ? g : -1;
        }
    }

    f32x4 acc[NT];
#pragma unroll
    for (int t = 0; t < NT; ++t) acc[t] = (f32x4){0.f, 0.f, 0.f, 0.f};

    const int h  = l >> 5;                // tap-half within pair
    const int m  = (l >> 1) & 15;         // row
    const int ch = l & 1;                 // 16B chunk

#pragma unroll
    for (int tb0 = 0; tb0 < TP; tb0 += BT) {
        // --- A DMAs: wave-private, 2 taps per instr
#pragma unroll
        for (int q = 0; q < BT/2; ++q) {
            const int v0 = __shfl(idx[tb0 + 2*q],     m);
            const int v1 = __shfl(idx[tb0 + 2*q + 1], m);
            const int row = h ? v1 : v0;
            const unsigned short* gp = fin + (ptrdiff_t)row*16 + ch*8;
            unsigned short* lp = Abuf + (w*BT + 2*q)*16*16;
            dma16(gp, lp);
        }
        // --- B DMAs: block-shared
        for (int q = w; q < NB; q += 4) {
            if constexpr (COUT == 16) {
                const int tap = tb0 + 2*q + h;
                const int tw = tap < T ? tap : T;
                const unsigned short* gp = wt + ((size_t)tw*COUT + m)*16 + ch*8;
                unsigned short* lp = Bbuf + (2*q)*COUT*16;
                dma16(gp, lp);
            } else {
                const int tap = tb0 + q;
                const int tw = tap < T ? tap : T;
                const int r = l >> 1;     // 0..31
                const unsigned short* gp = wt + ((size_t)tw*COUT + r)*16 + ch*8;
                unsigned short* lp = Bbuf + q*COUT*16;
                dma16(gp, lp);
            }
        }
        __syncthreads();
        // --- compute: tap pair per MFMA
#pragma unroll
        for (int jp = 0; jp < BT/2; ++jp) {
            const int ts = 2*jp + (quad >> 1);
            bf16x8 a = *(const bf16x8*)(Abuf + ((w*BT + ts)*16 + n)*16 + (quad & 1)*8);
#pragma unroll
            for (int t = 0; t < NT; ++t) {
                bf16x8 b = *(const bf16x8*)(Bbuf + (ts*COUT + t*16 + n)*16 + (quad & 1)*8);
                acc[t] = __builtin_amdgcn_mfma_f32_16x16x32_bf16(a, b, acc[t], 0, 0, 0);
            }
        }
        __syncthreads();
    }

#pragma unroll
    for (int t = 0; t < NT; ++t)
#pragma unroll
        for (int r = 0; r < 4; ++r) {
            const int p = pbase + quad*4 + r;
            if (p < n_out) out[(size_t)p * COUT + t*16 + n] = acc[t][r];
        }

#pragma unroll
    for (int t = 0; t < NT; ++t) {
        float s1 = 0.f, s2 = 0.f;
#pragma unroll
        for (int r = 0; r < 4; ++r) {
            const int p = pbase + quad*4 + r;
            if (p < n_out) { const float v = acc[t][r]; s1 += v; s2 += v*v; }
        }
        s1 += __shfl_xor(s1, 16); s2 += __shfl_xor(s2, 16);
        s1 += __shfl_xor(s1, 32); s2 += __shfl_xor(s2, 32);
        if (quad == 0) {
            atomicAdd(&ls[t*16 + n], s1);
            atomicAdd(&ls[COUT + t*16 + n], s2);
        }
    }
    __syncthreads();
    if (threadIdx.x < 2*COUT) atomicAdd(&stats[threadIdx.x], ls[threadIdx.x]);
}

// ---------------------------------------------------------------------------
// LDS path, CIN>=32. As R9, plus quad-deduped grid lookups.
// ---------------------------------------------------------------------------
template<int CIN, int COUT, int BT, int KD, int KH, int KW>
__global__ __launch_bounds__(256, 2) void sp_conv_lds(
    const unsigned short* __restrict__ fin, const int* __restrict__ grid,
    const int* __restrict__ oc, int n_out,
    const unsigned short* __restrict__ wt, float* __restrict__ out,
    float* __restrict__ stats,
    int D, int H, int W, int sz, int sy, int sx, int pz, int py, int px)
{
    constexpr int T    = KD*KH*KW;
    constexpr int TP   = ((T + BT - 1)/BT)*BT;
    constexpr int NT   = COUT/16;
    constexpr int S    = CIN/32;
    constexpr int LPR  = CIN/8;          // lanes per row
    constexpr int RPD  = 64/LPR;         // rows per DMA
    constexpr int ADMA = 16/RPD;         // A DMAs per tap per wave
    constexpr int BDMA = COUT/RPD;       // B DMAs per tap (block total)

    __shared__ unsigned short Abuf[4*BT*16*CIN];
    __shared__ unsigned short Bbuf[BT*COUT*CIN];
    __shared__ float ls[2*COUT];

    const int l     = threadIdx.x & 63;
    const int w     = threadIdx.x >> 6;
    const int n     = l & 15;
    const int quad  = l >> 4;
    const int pbase = blockIdx.x * 64 + w * 16;

    if (threadIdx.x < 2*COUT) ls[threadIdx.x] = 0.f;

    // --- tap indices on quad 0 only
    int idx[TP];
    if (quad == 0) {
        int pc = pbase + n;
        if (pc > n_out - 1) pc = n_out - 1;
        const int4 cc = ((const int4*)oc)[pc];
        const int* gb = grid + cc.x * (D * H * W);
        const int iz0 = cc.y * sz - pz;
        const int iy0 = cc.z * sy - py;
        const int ix0 = cc.w * sx - px;
#pragma unroll
        for (int tap = 0; tap < TP; ++tap) {
            const int te = tap < T ? tap : 0;
            const int kd = te/(KH*KW), kr = te%(KH*KW), kh = kr/KW, kw = kr%KW;
            const int iz = iz0 + kd, iy = iy0 + kh, ix = ix0 + kw;
            const bool ok = (tap < T) && (unsigned)iz < (unsigned)D &&
                            (unsigned)iy < (unsigned)H && (unsigned)ix < (unsigned)W;
            const int cz = iz < 0 ? 0 : (iz >= D ? D-1 : iz);
            const int cy = iy < 0 ? 0 : (iy >= H ? H-1 : iy);
            const int cx = ix < 0 ? 0 : (ix >= W ? W-1 : ix);
            const int g = gb[(cz*H + cy)*W + cx];
            idx[tap] = ok ? g : -1;
        }
    }

    f32x4 acc[NT];
#pragma unroll
    for (int t = 0; t < NT; ++t) acc[t] = (f32x4){0.f, 0.f, 0.f, 0.f};

#pragma unroll
    for (int tb0 = 0; tb0 < TP; tb0 += BT) {
        // --- A DMAs: full rows, row fanned out via width-64 shfl from quad 0
#pragma unroll
        for (int j = 0; j < BT; ++j) {
#pragma unroll
            for (int d = 0; d < ADMA; ++d) {
                const int m  = d*RPD + l/LPR;
                const int i0 = __shfl(idx[tb0+j], m);
                const int slot = (l % LPR) ^ (m % LPR);
                const unsigned short* gp = fin + (ptrdiff_t)i0*CIN + slot*8;
                unsigned short* lp = Abuf + ((w*BT + j)*16 + d*RPD)*CIN;
                dma16(gp, lp);
            }
        }
        // --- B DMAs: block-shared
        for (int q = w; q < BT*BDMA; q += 4) {
            const int j = q / BDMA, d = q % BDMA;
            const int t = tb0 + j;
            const int tw = t < T ? t : T;
            const int r  = d*RPD + l/LPR;
            const int slot = (l % LPR) ^ (r % LPR);
            const unsigned short* gp = wt + ((size_t)tw*COUT + r)*CIN + slot*8;
            unsigned short* lp = Bbuf + (j*COUT + d*RPD)*CIN;
            dma16(gp, lp);
        }
        __syncthreads();
        // --- compute
#pragma unroll
        for (int j = 0; j < BT; ++j) {
            const unsigned short* Aw = Abuf + (w*BT + j)*16*CIN;
            const unsigned short* Bw = Bbuf + j*COUT*CIN;
#pragma unroll
            for (int s = 0; s < S; ++s) {
                const int c = s*4 + quad;
                bf16x8 a = *(const bf16x8*)(Aw + n*CIN + ((c ^ (n % LPR)) * 8));
#pragma unroll
                for (int t = 0; t < NT; ++t) {
                    const int r = t*16 + n;
                    bf16x8 b = *(const bf16x8*)(Bw + r*CIN + ((c ^ (r % LPR)) * 8));
                    acc[t] = __builtin_amdgcn_mfma_f32_16x16x32_bf16(a, b, acc[t], 0, 0, 0);
                }
            }
        }
        __syncthreads();
    }

#pragma unroll
    for (int t = 0; t < NT; ++t)
#pragma unroll
        for (int r = 0; r < 4; ++r) {
            const int p = pbase + quad*4 + r;
            if (p < n_out) out[(size_t)p * COUT + t*16 + n] = acc[t][r];
        }

#pragma unroll
    for (int t = 0; t < NT; ++t) {
        float s1 = 0.f, s2 = 0.f;
#pragma unroll
        for (int r = 0; r < 4; ++r) {
            const int p = pbase + quad*4 + r;
            if (p < n_out) { const float v = acc[t][r]; s1 += v; s2 += v*v; }
        }
        s1 += __shfl_xor(s1, 16); s2 += __shfl_xor(s2, 16);
        s1 += __shfl_xor(s1, 32); s2 += __shfl_xor(s2, 32);
        if (quad == 0) {
            atomicAdd(&ls[t*16 + n], s1);
            atomicAdd(&ls[COUT + t*16 + n], s2);
        }
    }
    __syncthreads();
    if (threadIdx.x < 2*COUT) atomicAdd(&stats[threadIdx.x], ls[threadIdx.x]);
}

template<int C>
__global__ __launch_bounds__(256) void reduce_stats(const float* __restrict__ x, int nn,
                                                    float* __restrict__ stats)
{
    constexpr int R = 256 / C;
    __shared__ float s1[256];
    __shared__ float s2[256];
    const int c = threadIdx.x % C;
    const int r = threadIdx.x / C;
    float a1 = 0.f, a2 = 0.f;
    for (int i = blockIdx.x * R + r; i < nn; i += R * gridDim.x) {
        float v = x[(size_t)i*C + c];
        a1 += v;
        a2 += v * v;
    }
    s1[threadIdx.x] = a1;
    s2[threadIdx.x] = a2;
    __syncthreads();
    for (int off = 128; off >= C; off >>= 1) {
        if (threadIdx.x < off) {
            s1[threadIdx.x] += s1[threadIdx.x + off];
            s2[threadIdx.x] += s2[threadIdx.x + off];
        }
        __syncthreads();
    }
    if (threadIdx.x < C) {
        atomicAdd(&stats[c],     s1[threadIdx.x]);
        atomicAdd(&stats[C + c], s2[threadIdx.x]);
    }
}

__device__ inline void stv4(float* p, float4 v) { *(float4*)p = v; }
__device__ inline void stv4(unsigned short* p, float4 v) {
    bf16x4s o;
    o.x = (short)f2bf(v.x); o.y = (short)f2bf(v.y);
    o.z = (short)f2bf(v.z); o.w = (short)f2bf(v.w);
    *(bf16x4s*)p = o;
}

template<int C, typename OUT>
__global__ __launch_bounds__(256) void bn_relu_apply(const float* __restrict__ x,
                                                     OUT* __restrict__ y, int nn,
                                                     const float* __restrict__ stats,
                                                     const float* __restrict__ gamma,
                                                     const float* __restrict__ beta)
{
    const size_t q = (size_t)blockIdx.x * blockDim.x + threadIdx.x;
    if (q >= (size_t)nn * (C/4)) return;
    const int c = (int)(q % (size_t)(C/4)) * 4;
    const float inv_n = 1.f / (float)nn;
    const float4 xv = *(const float4*)(x + q*4);
    const float4 s1 = *(const float4*)(stats + c);
    const float4 s2 = *(const float4*)(stats + C + c);
    const float4 gm = *(const float4*)(gamma + c);
    const float4 bt = *(const float4*)(beta + c);
    float4 o;
    { float mu=s1.x*inv_n, var=s2.x*inv_n-mu*mu, g=gm.x*rsqrtf(var+1e-3f);
      float v=(xv.x-mu)*g+bt.x; o.x = v>0.f? v:0.f; }
    { float mu=s1.y*inv_n, var=s2.y*inv_n-mu*mu, g=gm.y*rsqrtf(var+1e-3f);
      float v=(xv.y-mu)*g+bt.y; o.y = v>0.f? v:0.f; }
    { float mu=s1.z*inv_n, var=s2.z*inv_n-mu*mu, g=gm.z*rsqrtf(var+1e-3f);
      float v=(xv.z-mu)*g+bt.z; o.z = v>0.f? v:0.f; }
    { float mu=s1.w*inv_n, var=s2.w*inv_n-mu*mu, g=gm.w*rsqrtf(var+1e-3f);
      float v=(xv.w-mu)*g+bt.w; o.w = v>0.f? v:0.f; }
    stv4(y + q*4, o);
}

extern "C" void kernel_launch(void* const* d_in, const int* in_sizes, int n_in,
                              void* d_out, int out_size, void* d_ws, size_t ws_size,
                              hipStream_t stream) {
    const float* WPTR[12] = {
        (const float*)d_in[1], (const float*)d_in[2], (const float*)d_in[3],
        (const float*)d_in[4], (const float*)d_in[5], (const float*)d_in[6],
        (const float*)d_in[7], (const float*)d_in[8], (const float*)d_in[9],
        (const float*)d_in[10], (const float*)d_in[11], (const float*)d_in[12] };
    const float* vf    = (const float*)d_in[0];
    const float* gamma = (const float*)d_in[13];
    const float* beta  = (const float*)d_in[14];
    const int* c1 = (const int*)d_in[15];
    const int* c2 = (const int*)d_in[16];
    const int* c3 = (const int*)d_in[17];
    const int* c4 = (const int*)d_in[18];
    const int* c5 = (const int*)d_in[19];
    const int N1 = in_sizes[15] / 4;
    const int N2 = in_sizes[16] / 4;
    const int N3 = in_sizes[17] / 4;
    const int N4 = in_sizes[18] / 4;
    const int N5 = in_sizes[19] / 4;

    static const int LT[12]  = {27,27,27,27,27,27,27,27,27,27,27,3};
    static const int LCI[12] = {4,16,16,32,32,32,64,64,64,64,64,64};
    static const int LCO[12] = {16,16,32,32,32,64,64,64,64,64,64,128};

    const size_t G1 = (size_t)2*41*160*160;
    const size_t G2 = (size_t)2*21*80*80;
    const size_t G3 = (size_t)2*11*40*40;
    const size_t G4 = (size_t)2*5*20*20;
    int* grid1 = (int*)d_ws;
    int* grid2 = grid1 + G1;
    int* grid3 = grid2 + G2;
    int* grid4 = grid3 + G3;
    float* stats = (float*)(grid4 + G4);

    size_t maxE = (size_t)N1*16;
    if ((size_t)N2*32  > maxE) maxE = (size_t)N2*32;
    if ((size_t)N3*64  > maxE) maxE = (size_t)N3*64;
    if ((size_t)N4*64  > maxE) maxE = (size_t)N4*64;
    if ((size_t)N5*128 > maxE) maxE = (size_t)N5*128;
    maxE = (maxE + 7) & ~(size_t)7;

    float* raw = stats + 12*256;
    unsigned short* padA = (unsigned short*)(raw + maxE);
    unsigned short* fA   = padA + 128;              // zero row at fA - CIN
    unsigned short* padB = fA + maxE;
    unsigned short* fB   = padB + 128;
    unsigned short* wtb  = fB + maxE;
    size_t wtoff[12];
    {
        size_t o = 0;
        for (int i = 1; i < 12; ++i) {
            wtoff[i] = o;
            o += (size_t)(LT[i] + 1) * LCI[i] * LCO[i];
        }
    }

    hipMemsetAsync(grid1, 0xFF, (G1+G2+G3+G4)*sizeof(int), stream);
    hipMemsetAsync(stats, 0, 12*256*sizeof(float), stream);
    hipMemsetAsync(padA, 0, 128*sizeof(unsigned short), stream);
    hipMemsetAsync(padB, 0, 128*sizeof(unsigned short), stream);

    {
        ScatterArgs sa;
        sa.coords[0]=c1; sa.coords[1]=c2; sa.coords[2]=c3; sa.coords[3]=c4;
        sa.grid[0]=grid1; sa.grid[1]=grid2; sa.grid[2]=grid3; sa.grid[3]=grid4;
        sa.n[0]=N1; sa.n[1]=N2; sa.n[2]=N3; sa.n[3]=N4;
        sa.D[0]=41; sa.H[0]=160; sa.W[0]=160;
        sa.D[1]=21; sa.H[1]= 80; sa.W[1]= 80;
        sa.D[2]=11; sa.H[2]= 40; sa.W[2]= 40;
        sa.D[3]= 5; sa.H[3]= 20; sa.W[3]= 20;
        int mx = N1; if (N2>mx) mx=N2; if (N3>mx) mx=N3; if (N4>mx) mx=N4;
        dim3 g((mx + 255)/256, 4);
        scatter_grid_all<<<g, 256, 0, stream>>>(sa);
    }
    {
        PrepArgs pa;
        int mx = 0;
        for (int i = 1; i < 12; ++i) {
            pa.src[i-1] = WPTR[i];
            pa.dst[i-1] = wtb + wtoff[i];
            pa.T[i-1] = LT[i]; pa.CIN[i-1] = LCI[i]; pa.COUT[i-1] = LCO[i];
            pa.total[i-1] = (LT[i]+1)*LCI[i]*LCO[i];
            if (pa.total[i-1] > mx) mx = pa.total[i-1];
        }
        dim3 g((mx + 255)/256, 11);
        prep_w_all<<<g, 256, 0, stream>>>(pa);
    }

    enum { GOFF_0 = 0, GOFF_1 = 16, GOFF_2 = 32, GOFF_3 = 64, GOFF_4 = 96, GOFF_5 = 128,
           GOFF_6 = 192, GOFF_7 = 256, GOFF_8 = 320, GOFF_9 = 384, GOFF_10 = 448, GOFF_11 = 512 };

#define APPLY(i, COUT, NP, FOUT_T, FOUT) \
    bn_relu_apply<COUT, FOUT_T><<<(((size_t)(NP)*(COUT)/4) + 255)/256, 256, 0, stream>>>( \
        raw, FOUT, NP, stats + (i)*256, gamma + GOFF_##i, beta + GOFF_##i);

    sp_conv0<<<((size_t)N1*16 + 255)/256, 256, 0, stream>>>(vf, grid1, c1, N1, WPTR[0], raw, 41,160,160);
    { int rb = (N1 + 15)/16; if (rb > 240) rb = 240;
      reduce_stats<16><<<rb, 256, 0, stream>>>(raw, N1, stats + 0*256); }
    APPLY(0, 16, N1, unsigned short, fA);

#define CONVS(i, COUT, FIN, GRD, OC, NP, D,H,W, SZ,SY,SX, PZ,PY,PX) \
    sp_conv_lds16<COUT><<<((NP)+63)/64, 256, 0, stream>>>( \
        FIN, GRD, OC, NP, wtb + wtoff[i], raw, stats + (i)*256, D,H,W, SZ,SY,SX, PZ,PY,PX);

#define CONVL(i, CIN, COUT, BT, KD,KH,KW, FIN, GRD, OC, NP, D,H,W, SZ,SY,SX, PZ,PY,PX) \
    sp_conv_lds<CIN,COUT,BT,KD,KH,KW><<<((NP)+63)/64, 256, 0, stream>>>( \
        FIN, GRD, OC, NP, wtb + wtoff[i], raw, stats + (i)*256, D,H,W, SZ,SY,SX, PZ,PY,PX);

    CONVS( 1, 16,       fA, grid1, c1, N1, 41,160,160, 1,1,1, 1,1,1); APPLY( 1, 16, N1, unsigned short, fB);
    CONVS( 2, 32,       fB, grid1, c2, N2, 41,160,160, 2,2,2, 1,1,1); APPLY( 2, 32, N2, unsigned short, fA);
    CONVL ( 3, 32, 32, 7, 3,3,3, fA, grid2, c2, N2, 21, 80, 80, 1,1,1, 1,1,1); APPLY( 3, 32, N2, unsigned short, fB);
    CONVL ( 4, 32, 32, 7, 3,3,3, fB, grid2, c2, N2, 21, 80, 80, 1,1,1, 1,1,1); APPLY( 4, 32, N2, unsigned short, fA);
    CONVL ( 5, 32, 64, 7, 3,3,3, fA, grid2, c3, N3, 21, 80, 80, 2,2,2, 1,1,1); APPLY( 5, 64, N3, unsigned short, fB);
    CONVL ( 6, 64, 64, 3, 3,3,3, fB, grid3, c3, N3, 11, 40, 40, 1,1,1, 1,1,1); APPLY( 6, 64, N3, unsigned short, fA);
    CONVL ( 7, 64, 64, 3, 3,3,3, fA, grid3, c3, N3, 11, 40, 40, 1,1,1, 1,1,1); APPLY( 7, 64, N3, unsigned short, fB);
    CONVL ( 8, 64, 64, 3, 3,3,3, fB, grid3, c4, N4, 11, 40, 40, 2,2,2, 0,1,1); APPLY( 8, 64, N4, unsigned short, fA);
    CONVL ( 9, 64, 64, 3, 3,3,3, fA, grid4, c4, N4,  5, 20, 20, 1,1,1, 1,1,1); APPLY( 9, 64, N4, unsigned short, fB);
    CONVL (10, 64, 64, 3, 3,3,3, fB, grid4, c4, N4,  5, 20, 20, 1,1,1, 1,1,1); APPLY(10, 64, N4, unsigned short, fA);
    CONVL (11, 64,128, 1, 3,1,1, fA, grid4, c5, N5,  5, 20, 20, 2,1,1, 0,0,0); APPLY(11, 128, N5, float, (float*)d_out);
#undef CONVS
#undef CONVL
#undef APPLY
}